// Round 1
// baseline (383.727 us; speedup 1.0000x reference)
//
#include <hip/hip_runtime.h>
#include <math.h>

#define B_ 4
#define C_ 256
#define N_ 2048
#define H_ 4
#define D_ 64

// ---------------------------------------------------------------------------
// Weight transpose: Wt[c][o] = W[o][c]  (256x256)
// ---------------------------------------------------------------------------
__global__ __launch_bounds__(1024) void transpose256(const float* __restrict__ W,
                                                     float* __restrict__ Wt) {
    __shared__ float t[32][33];
    const int bx = blockIdx.x * 32, by = blockIdx.y * 32;
    const int x = threadIdx.x, y = threadIdx.y;
    t[y][x] = W[(by + y) * C_ + bx + x];
    __syncthreads();
    Wt[(bx + y) * C_ + by + x] = t[x][y];
}

// ---------------------------------------------------------------------------
// 1x1 conv as GEMM: Y[b][o][n] = bias[o] + sum_c Wt[c][o] * X[b][c][n]
// Tile 64(o) x 64(n), BK=32. Block = 256 threads, each computes 4x4.
// ---------------------------------------------------------------------------
__global__ __launch_bounds__(256) void conv_gemm(const float* __restrict__ Wt,
                                                 const float* __restrict__ bias,
                                                 const float* __restrict__ X,
                                                 float* __restrict__ Y) {
    const int n0 = blockIdx.x * 64;
    const int o0 = blockIdx.y * 64;
    const int b  = blockIdx.z;
    __shared__ float Ws[32][64];   // [k][o]
    __shared__ float Xs[32][64];   // [k][n]
    const int tid = threadIdx.x;
    const int tx = tid & 15;       // n direction
    const int ty = tid >> 4;       // o direction
    float acc[4][4] = {};
    const float* Xb = X + (size_t)b * C_ * N_;

    for (int kb = 0; kb < C_; kb += 32) {
        __syncthreads();
#pragma unroll
        for (int p = 0; p < 2; ++p) {
            const int idx = tid + p * 256;
            const int k  = idx >> 4;
            const int c4 = (idx & 15) << 2;
            *(float4*)&Ws[k][c4] = *(const float4*)&Wt[(size_t)(kb + k) * C_ + o0 + c4];
            *(float4*)&Xs[k][c4] = *(const float4*)&Xb[(size_t)(kb + k) * N_ + n0 + c4];
        }
        __syncthreads();
#pragma unroll 8
        for (int k = 0; k < 32; ++k) {
            const float4 wv = *(const float4*)&Ws[k][ty << 2];
            const float4 xv = *(const float4*)&Xs[k][tx << 2];
            const float w[4]  = {wv.x, wv.y, wv.z, wv.w};
            const float xr[4] = {xv.x, xv.y, xv.z, xv.w};
#pragma unroll
            for (int i = 0; i < 4; ++i)
#pragma unroll
                for (int j = 0; j < 4; ++j)
                    acc[i][j] += w[i] * xr[j];
        }
    }
#pragma unroll
    for (int i = 0; i < 4; ++i) {
        const int o = o0 + (ty << 2) + i;
        const float bo = bias[o];
        float4 r;
        r.x = acc[i][0] + bo; r.y = acc[i][1] + bo;
        r.z = acc[i][2] + bo; r.w = acc[i][3] + bo;
        *(float4*)&Y[((size_t)b * C_ + o) * N_ + n0 + (tx << 2)] = r;
    }
}

// ---------------------------------------------------------------------------
// Flash attention (fp32). One block = one (b, h, 64-query tile).
// Channel layout: channel o = d*H_ + h (head_dim outer).
// Q is pre-scaled by 1/8 = 1/sqrt(D) at load (exact).
// ---------------------------------------------------------------------------
__global__ __launch_bounds__(256) void attn_kernel(const float* __restrict__ Q,
                                                   const float* __restrict__ K,
                                                   const float* __restrict__ V,
                                                   float* __restrict__ O) {
    const int n0 = blockIdx.x * 64;   // query tile
    const int h  = blockIdx.y;
    const int b  = blockIdx.z;

    __shared__ float Qs[64][64];   // [d][i]
    __shared__ float Ks[64][64];   // [d][j]
    __shared__ float Vt[64][68];   // [j][d]  (padded: 68*4=272B rows, 16B aligned)
    __shared__ float Pt[64][68];   // [j][i]

    const int tid = threadIdx.x;
    const int tx = tid & 15;       // score: j-block / output: d-block
    const int ty = tid >> 4;       // i-block (query rows)

    // ---- load Q tile (scaled), layout Qs[d][i]
#pragma unroll
    for (int p = 0; p < 4; ++p) {
        const int idx = tid + p * 256;
        const int d  = idx >> 4;
        const int c4 = (idx & 15) << 2;
        float4 v = *(const float4*)&Q[((size_t)b * C_ + d * H_ + h) * N_ + n0 + c4];
        v.x *= 0.125f; v.y *= 0.125f; v.z *= 0.125f; v.w *= 0.125f;
        *(float4*)&Qs[d][c4] = v;
    }

    float m_r[4], l_r[4];
    float accO[4][4] = {};
#pragma unroll
    for (int i = 0; i < 4; ++i) { m_r[i] = -INFINITY; l_r[i] = 0.f; }

    for (int kt = 0; kt < N_ / 64; ++kt) {
        const int m0 = kt * 64;
        __syncthreads();   // previous iteration's reads of Ks/Vt are done
        // ---- load K tile: Ks[d][j]
#pragma unroll
        for (int p = 0; p < 4; ++p) {
            const int idx = tid + p * 256;
            const int d  = idx >> 4;
            const int c4 = (idx & 15) << 2;
            *(float4*)&Ks[d][c4] =
                *(const float4*)&K[((size_t)b * C_ + d * H_ + h) * N_ + m0 + c4];
        }
        // ---- load V tile transposed: Vt[j][d]
#pragma unroll
        for (int p = 0; p < 4; ++p) {
            const int idx = tid + p * 256;
            const int d  = idx >> 4;
            const int j0 = (idx & 15) << 2;
            const float4 v =
                *(const float4*)&V[((size_t)b * C_ + d * H_ + h) * N_ + m0 + j0];
            Vt[j0 + 0][d] = v.x;
            Vt[j0 + 1][d] = v.y;
            Vt[j0 + 2][d] = v.z;
            Vt[j0 + 3][d] = v.w;
        }
        __syncthreads();

        // ---- scores: s[ii][jj] = sum_d Qs[d][ty*4+ii] * Ks[d][tx*4+jj]
        float s[4][4] = {};
#pragma unroll 8
        for (int d = 0; d < 64; ++d) {
            const float4 qv = *(const float4*)&Qs[d][ty << 2];
            const float4 kv = *(const float4*)&Ks[d][tx << 2];
            const float qa[4] = {qv.x, qv.y, qv.z, qv.w};
            const float ka[4] = {kv.x, kv.y, kv.z, kv.w};
#pragma unroll
            for (int i = 0; i < 4; ++i)
#pragma unroll
                for (int j = 0; j < 4; ++j)
                    s[i][j] += qa[i] * ka[j];
        }

        // ---- online softmax (rows = ty*4+ii, 16 lanes per row-group share it)
#pragma unroll
        for (int ii = 0; ii < 4; ++ii) {
            float mx = fmaxf(fmaxf(s[ii][0], s[ii][1]), fmaxf(s[ii][2], s[ii][3]));
            mx = fmaxf(mx, __shfl_xor(mx, 1));
            mx = fmaxf(mx, __shfl_xor(mx, 2));
            mx = fmaxf(mx, __shfl_xor(mx, 4));
            mx = fmaxf(mx, __shfl_xor(mx, 8));
            const float m_new = fmaxf(m_r[ii], mx);
            const float alpha = expf(m_r[ii] - m_new);
            float p[4], rs = 0.f;
#pragma unroll
            for (int jj = 0; jj < 4; ++jj) {
                p[jj] = expf(s[ii][jj] - m_new);
                rs += p[jj];
            }
            rs += __shfl_xor(rs, 1);
            rs += __shfl_xor(rs, 2);
            rs += __shfl_xor(rs, 4);
            rs += __shfl_xor(rs, 8);
            l_r[ii] = l_r[ii] * alpha + rs;
            m_r[ii] = m_new;
#pragma unroll
            for (int dd = 0; dd < 4; ++dd) accO[ii][dd] *= alpha;
            // write P transposed: Pt[j][i]
#pragma unroll
            for (int jj = 0; jj < 4; ++jj)
                Pt[(tx << 2) + jj][(ty << 2) + ii] = p[jj];
        }
        __syncthreads();   // Pt visible (also keeps waves in step for Ks/Vt reuse)

        // ---- PV: accO[ii][dd] += sum_j Pt[j][ty*4+ii] * Vt[j][tx*4+dd]
#pragma unroll 8
        for (int j = 0; j < 64; ++j) {
            const float4 pv = *(const float4*)&Pt[j][ty << 2];
            const float4 vv = *(const float4*)&Vt[j][tx << 2];
            const float pa[4] = {pv.x, pv.y, pv.z, pv.w};
            const float va[4] = {vv.x, vv.y, vv.z, vv.w};
#pragma unroll
            for (int i = 0; i < 4; ++i)
#pragma unroll
                for (int d = 0; d < 4; ++d)
                    accO[i][d] += pa[i] * va[d];
        }
    }

    // ---- epilogue: divide by l, stage transposed in Qs[d][i], write coalesced
    __syncthreads();   // everyone done reading Qs
#pragma unroll
    for (int ii = 0; ii < 4; ++ii) {
        const float inv_l = 1.0f / l_r[ii];
#pragma unroll
        for (int dd = 0; dd < 4; ++dd)
            Qs[(tx << 2) + dd][(ty << 2) + ii] = accO[ii][dd] * inv_l;
    }
    __syncthreads();
#pragma unroll
    for (int p = 0; p < 4; ++p) {
        const int idx = tid + p * 256;
        const int d  = idx >> 4;
        const int i4 = (idx & 15) << 2;
        const float4 v = *(const float4*)&Qs[d][i4];
        *(float4*)&O[((size_t)b * C_ + d * H_ + h) * N_ + n0 + i4] = v;
    }
}

// ---------------------------------------------------------------------------
extern "C" void kernel_launch(void* const* d_in, const int* in_sizes, int n_in,
                              void* d_out, int out_size, void* d_ws, size_t ws_size,
                              hipStream_t stream) {
    const float* query = (const float*)d_in[0];
    const float* key   = (const float*)d_in[1];
    const float* value = (const float*)d_in[2];
    const float* wq = (const float*)d_in[3];
    const float* bq = (const float*)d_in[4];
    const float* wk = (const float*)d_in[5];
    const float* bk = (const float*)d_in[6];
    const float* wv = (const float*)d_in[7];
    const float* bv = (const float*)d_in[8];
    const float* wm = (const float*)d_in[9];
    const float* bm = (const float*)d_in[10];

    float* out = (float*)d_out;
    float* ws  = (float*)d_ws;

    const size_t TEN = (size_t)B_ * C_ * N_;   // 2,097,152 floats
    float* qp  = out;                 // q projection scratch (consumed before final GEMM writes out)
    float* kp  = ws;
    float* vp  = ws + TEN;
    float* ao  = ws + 2 * TEN;
    float* wqT = ws + 3 * TEN;
    float* wkT = wqT + C_ * C_;
    float* wvT = wkT + C_ * C_;
    float* wmT = wvT + C_ * C_;

    dim3 tb(32, 32);
    dim3 tg(8, 8);
    transpose256<<<tg, tb, 0, stream>>>(wq, wqT);
    transpose256<<<tg, tb, 0, stream>>>(wk, wkT);
    transpose256<<<tg, tb, 0, stream>>>(wv, wvT);
    transpose256<<<tg, tb, 0, stream>>>(wm, wmT);

    dim3 gg(N_ / 64, C_ / 64, B_);
    dim3 gb(256);
    conv_gemm<<<gg, gb, 0, stream>>>(wqT, bq, query, qp);
    conv_gemm<<<gg, gb, 0, stream>>>(wkT, bk, key,   kp);
    conv_gemm<<<gg, gb, 0, stream>>>(wvT, bv, value, vp);

    attn_kernel<<<dim3(N_ / 64, H_, B_), gb, 0, stream>>>(qp, kp, vp, ao);

    conv_gemm<<<gg, gb, 0, stream>>>(wmT, bm, ao, out);
}

// Round 2
// 330.532 us; speedup vs baseline: 1.1609x; 1.1609x over previous
//
#include <hip/hip_runtime.h>
#include <math.h>

#define B_ 4
#define C_ 256
#define N_ 2048
#define H_ 4
#define D_ 64

typedef __attribute__((ext_vector_type(8))) short bf16x8;
typedef __attribute__((ext_vector_type(4))) float f32x4;

__device__ __forceinline__ ushort f2bf(float x) {
    uint u = __float_as_uint(x);
    uint r = (u + 0x7fffu + ((u >> 16) & 1u)) >> 16;
    return (ushort)r;
}
__device__ __forceinline__ float bf2f(ushort u) {
    return __uint_as_float((uint)u << 16);
}
__device__ __forceinline__ uint pack2(float a, float b) {
    return (uint)f2bf(a) | ((uint)f2bf(b) << 16);
}

// ---------------------------------------------------------------------------
// Weight transpose: Wt[c][o] = W[o][c]  (256x256)
// ---------------------------------------------------------------------------
__global__ __launch_bounds__(1024) void transpose256(const float* __restrict__ W,
                                                     float* __restrict__ Wt) {
    __shared__ float t[32][33];
    const int bx = blockIdx.x * 32, by = blockIdx.y * 32;
    const int x = threadIdx.x, y = threadIdx.y;
    t[y][x] = W[(by + y) * C_ + bx + x];
    __syncthreads();
    Wt[(bx + y) * C_ + by + x] = t[x][y];
}

// ---------------------------------------------------------------------------
// 1x1 conv as GEMM (fp32): Y[b][o][n] = bias[o] + sum_c Wt[c][o] * X[b][c][n]
// ---------------------------------------------------------------------------
__global__ __launch_bounds__(256) void conv_gemm(const float* __restrict__ Wt,
                                                 const float* __restrict__ bias,
                                                 const float* __restrict__ X,
                                                 float* __restrict__ Y) {
    const int n0 = blockIdx.x * 64;
    const int o0 = blockIdx.y * 64;
    const int b  = blockIdx.z;
    __shared__ float Ws[32][64];
    __shared__ float Xs[32][64];
    const int tid = threadIdx.x;
    const int tx = tid & 15;
    const int ty = tid >> 4;
    float acc[4][4] = {};
    const float* Xb = X + (size_t)b * C_ * N_;

    for (int kb = 0; kb < C_; kb += 32) {
        __syncthreads();
#pragma unroll
        for (int p = 0; p < 2; ++p) {
            const int idx = tid + p * 256;
            const int k  = idx >> 4;
            const int c4 = (idx & 15) << 2;
            *(float4*)&Ws[k][c4] = *(const float4*)&Wt[(size_t)(kb + k) * C_ + o0 + c4];
            *(float4*)&Xs[k][c4] = *(const float4*)&Xb[(size_t)(kb + k) * N_ + n0 + c4];
        }
        __syncthreads();
#pragma unroll 8
        for (int k = 0; k < 32; ++k) {
            const float4 wv = *(const float4*)&Ws[k][ty << 2];
            const float4 xv = *(const float4*)&Xs[k][tx << 2];
            const float w[4]  = {wv.x, wv.y, wv.z, wv.w};
            const float xr[4] = {xv.x, xv.y, xv.z, xv.w};
#pragma unroll
            for (int i = 0; i < 4; ++i)
#pragma unroll
                for (int j = 0; j < 4; ++j)
                    acc[i][j] += w[i] * xr[j];
        }
    }
#pragma unroll
    for (int i = 0; i < 4; ++i) {
        const int o = o0 + (ty << 2) + i;
        const float bo = bias[o];
        float4 r;
        r.x = acc[i][0] + bo; r.y = acc[i][1] + bo;
        r.z = acc[i][2] + bo; r.w = acc[i][3] + bo;
        *(float4*)&Y[((size_t)b * C_ + o) * N_ + n0 + (tx << 2)] = r;
    }
}

// ---------------------------------------------------------------------------
// 1x1 conv variant for V: writes packed bf16 hi/lo at Vpack[b][h][d][n]
// (o = d*H + h). Coalesced: rows along n.
// ---------------------------------------------------------------------------
__global__ __launch_bounds__(256) void conv_gemm_v(const float* __restrict__ Wt,
                                                   const float* __restrict__ bias,
                                                   const float* __restrict__ X,
                                                   ushort* __restrict__ Vh,
                                                   ushort* __restrict__ Vl) {
    const int n0 = blockIdx.x * 64;
    const int o0 = blockIdx.y * 64;
    const int b  = blockIdx.z;
    __shared__ float Ws[32][64];
    __shared__ float Xs[32][64];
    const int tid = threadIdx.x;
    const int tx = tid & 15;
    const int ty = tid >> 4;
    float acc[4][4] = {};
    const float* Xb = X + (size_t)b * C_ * N_;

    for (int kb = 0; kb < C_; kb += 32) {
        __syncthreads();
#pragma unroll
        for (int p = 0; p < 2; ++p) {
            const int idx = tid + p * 256;
            const int k  = idx >> 4;
            const int c4 = (idx & 15) << 2;
            *(float4*)&Ws[k][c4] = *(const float4*)&Wt[(size_t)(kb + k) * C_ + o0 + c4];
            *(float4*)&Xs[k][c4] = *(const float4*)&Xb[(size_t)(kb + k) * N_ + n0 + c4];
        }
        __syncthreads();
#pragma unroll 8
        for (int k = 0; k < 32; ++k) {
            const float4 wv = *(const float4*)&Ws[k][ty << 2];
            const float4 xv = *(const float4*)&Xs[k][tx << 2];
            const float w[4]  = {wv.x, wv.y, wv.z, wv.w};
            const float xr[4] = {xv.x, xv.y, xv.z, xv.w};
#pragma unroll
            for (int i = 0; i < 4; ++i)
#pragma unroll
                for (int j = 0; j < 4; ++j)
                    acc[i][j] += w[i] * xr[j];
        }
    }
#pragma unroll
    for (int i = 0; i < 4; ++i) {
        const int o = o0 + (ty << 2) + i;
        const int hh = o & 3;
        const int dd = o >> 2;
        const float bo = bias[o];
        float v[4];
#pragma unroll
        for (int j = 0; j < 4; ++j) v[j] = acc[i][j] + bo;
        ushort h0 = f2bf(v[0]), h1 = f2bf(v[1]), h2 = f2bf(v[2]), h3 = f2bf(v[3]);
        uint2 hw, lw;
        hw.x = (uint)h0 | ((uint)h1 << 16);
        hw.y = (uint)h2 | ((uint)h3 << 16);
        lw.x = (uint)f2bf(v[0] - bf2f(h0)) | ((uint)f2bf(v[1] - bf2f(h1)) << 16);
        lw.y = (uint)f2bf(v[2] - bf2f(h2)) | ((uint)f2bf(v[3] - bf2f(h3)) << 16);
        const size_t ro = ((size_t)((b * H_ + hh) * D_ + dd)) * N_ + n0 + (tx << 2);
        *(uint2*)&Vh[ro] = hw;
        *(uint2*)&Vl[ro] = lw;
    }
}

// ---------------------------------------------------------------------------
// Repack Q/K: fp32 X[b][c][n] (c = d*H+h) -> bf16 hi/lo at [b][h][n][d],
// with scale folded in (Q gets log2(e)/8, K gets 1).
// ---------------------------------------------------------------------------
__global__ __launch_bounds__(256) void repack_qk(const float* __restrict__ X,
                                                 ushort* __restrict__ Oh,
                                                 ushort* __restrict__ Ol,
                                                 float scale) {
    __shared__ float T[64][68];
    const int n0 = blockIdx.x * 64;
    const int h  = blockIdx.y;
    const int b  = blockIdx.z;
    const int t  = threadIdx.x;

    const int dr = t >> 2;
    const int c0 = (t & 3) << 4;
    const float* src = X + ((size_t)(b * C_ + dr * H_ + h)) * N_ + n0 + c0;
#pragma unroll
    for (int p = 0; p < 4; ++p) {
        *(float4*)&T[dr][c0 + p * 4] = *(const float4*)(src + p * 4);
    }
    __syncthreads();

    const int n  = t >> 2;
    const int d0 = (t & 3) << 4;
    uint hu[8], lu[8];
#pragma unroll
    for (int e2 = 0; e2 < 8; ++e2) {
        const float x0 = T[d0 + 2 * e2][n] * scale;
        const float x1 = T[d0 + 2 * e2 + 1][n] * scale;
        const ushort h0 = f2bf(x0), h1 = f2bf(x1);
        hu[e2] = (uint)h0 | ((uint)h1 << 16);
        lu[e2] = (uint)f2bf(x0 - bf2f(h0)) | ((uint)f2bf(x1 - bf2f(h1)) << 16);
    }
    const size_t off = ((size_t)(b * H_ + h) * N_ + n0 + n) * D_ + d0;
    *(uint4*)(Oh + off)     = make_uint4(hu[0], hu[1], hu[2], hu[3]);
    *(uint4*)(Oh + off + 8) = make_uint4(hu[4], hu[5], hu[6], hu[7]);
    *(uint4*)(Ol + off)     = make_uint4(lu[0], lu[1], lu[2], lu[3]);
    *(uint4*)(Ol + off + 8) = make_uint4(lu[4], lu[5], lu[6], lu[7]);
}

// ---------------------------------------------------------------------------
// MFMA flash attention. Block = 256 threads = 4 waves; each wave owns 16
// query rows; K-tile = 64 keys. Computes S^T = mfma(A=K, B=Q) with hi/lo
// 3-product split; softmax in exp2 domain (scale pre-folded into Q);
// O^T = mfma(A=V^T hi/lo, B=P^T). No LDS, no barriers — K/V/Q fragments read
// straight from packed global (L2-resident), P rearranged via shuffles.
// ---------------------------------------------------------------------------
__global__ __launch_bounds__(256) void attn_mfma(const ushort* __restrict__ Qh,
                                                 const ushort* __restrict__ Ql,
                                                 const ushort* __restrict__ Kh,
                                                 const ushort* __restrict__ Kl,
                                                 const ushort* __restrict__ Vh,
                                                 const ushort* __restrict__ Vl,
                                                 float* __restrict__ Oo) {
    const int bid = blockIdx.x;
    // XCD-aware swizzle: all 32 q-tile blocks of a (b,h) pair land on one XCD.
    const int L  = (bid & 7) * 64 + (bid >> 3);
    const int qt = L & 31;
    const int bh = L >> 5;

    const int tid  = threadIdx.x;
    const int wv   = tid >> 6;
    const int lane = tid & 63;
    const int li   = lane & 15;
    const int g    = lane >> 4;
    const int i0   = qt * 64 + wv * 16;

    // Q B-fragments (row i = i0+li, k-range d = g*8 + e + 32*ks), hi & lo.
    const size_t qoff = ((size_t)bh * N_ + i0 + li) * D_ + g * 8;
    const bf16x8 q_h0 = *(const bf16x8*)(Qh + qoff);
    const bf16x8 q_h1 = *(const bf16x8*)(Qh + qoff + 32);
    const bf16x8 q_l0 = *(const bf16x8*)(Ql + qoff);
    const bf16x8 q_l1 = *(const bf16x8*)(Ql + qoff + 32);

    const ushort* Kh_b = Kh + (size_t)bh * N_ * D_;
    const ushort* Kl_b = Kl + (size_t)bh * N_ * D_;
    const ushort* Vh_b = Vh + (size_t)bh * D_ * N_;
    const ushort* Vl_b = Vl + (size_t)bh * D_ * N_;

    const f32x4 z = {0.f, 0.f, 0.f, 0.f};
    f32x4 accO[4] = {z, z, z, z};
    float mrun = -1e30f, lrun = 0.f;

    for (int kt = 0; kt < N_ / 64; ++kt) {
        const int jbase = kt * 64;

        // ---- K A-fragments (row j = jt*16+li, k d = g*8+e+32ks)
        bf16x8 kfh[4][2], kfl[4][2];
#pragma unroll
        for (int jt = 0; jt < 4; ++jt) {
            const size_t ro = (size_t)(jbase + jt * 16 + li) * D_ + g * 8;
            kfh[jt][0] = *(const bf16x8*)(Kh_b + ro);
            kfh[jt][1] = *(const bf16x8*)(Kh_b + ro + 32);
            kfl[jt][0] = *(const bf16x8*)(Kl_b + ro);
            kfl[jt][1] = *(const bf16x8*)(Kl_b + ro + 32);
        }

        // ---- QK^T (transposed scores), 3-product hi/lo split
        f32x4 s[4];
#pragma unroll
        for (int jt = 0; jt < 4; ++jt) {
            f32x4 a = z;
            a = __builtin_amdgcn_mfma_f32_16x16x32_bf16(kfh[jt][0], q_l0, a, 0, 0, 0);
            a = __builtin_amdgcn_mfma_f32_16x16x32_bf16(kfl[jt][0], q_h0, a, 0, 0, 0);
            a = __builtin_amdgcn_mfma_f32_16x16x32_bf16(kfh[jt][0], q_h0, a, 0, 0, 0);
            a = __builtin_amdgcn_mfma_f32_16x16x32_bf16(kfh[jt][1], q_l1, a, 0, 0, 0);
            a = __builtin_amdgcn_mfma_f32_16x16x32_bf16(kfl[jt][1], q_h1, a, 0, 0, 0);
            a = __builtin_amdgcn_mfma_f32_16x16x32_bf16(kfh[jt][1], q_h1, a, 0, 0, 0);
            s[jt] = a;
        }

        // ---- V A-fragments (row d = dt*16+li, k j = g*8+e+32ks) — issue early
        bf16x8 vfh[4][2], vfl[4][2];
#pragma unroll
        for (int dt = 0; dt < 4; ++dt) {
            const size_t vo = (size_t)(dt * 16 + li) * N_ + jbase + g * 8;
            vfh[dt][0] = *(const bf16x8*)(Vh_b + vo);
            vfh[dt][1] = *(const bf16x8*)(Vh_b + vo + 32);
            vfl[dt][0] = *(const bf16x8*)(Vl_b + vo);
            vfl[dt][1] = *(const bf16x8*)(Vl_b + vo + 32);
        }

        // ---- online softmax in exp2 domain. Lane holds S^T[j][i]:
        // j = jbase + jt*16 + 4g + r, i = i0 + li.
        float mx = -1e30f;
#pragma unroll
        for (int jt = 0; jt < 4; ++jt)
#pragma unroll
            for (int r = 0; r < 4; ++r)
                mx = fmaxf(mx, s[jt][r]);
        mx = fmaxf(mx, __shfl_xor(mx, 16));
        mx = fmaxf(mx, __shfl_xor(mx, 32));
        const float mnew  = fmaxf(mrun, mx);
        const float alpha = exp2f(mrun - mnew);
        mrun = mnew;

        float p[4][4];
        float rs = 0.f;
#pragma unroll
        for (int jt = 0; jt < 4; ++jt)
#pragma unroll
            for (int r = 0; r < 4; ++r) {
                p[jt][r] = exp2f(s[jt][r] - mnew);
                rs += p[jt][r];
            }
        rs += __shfl_xor(rs, 16);
        rs += __shfl_xor(rs, 32);
        lrun = lrun * alpha + rs;
#pragma unroll
        for (int dt = 0; dt < 4; ++dt) {
            accO[dt][0] *= alpha; accO[dt][1] *= alpha;
            accO[dt][2] *= alpha; accO[dt][3] *= alpha;
        }

        // ---- pack P to bf16 pairs: pk[jt][c] = (p[jt][2c], p[jt][2c+1])
        uint pk[4][2];
#pragma unroll
        for (int jt = 0; jt < 4; ++jt) {
            pk[jt][0] = pack2(p[jt][0], p[jt][1]);
            pk[jt][1] = pack2(p[jt][2], p[jt][3]);
        }

        // ---- build P^T B-fragments via shuffles.
        // Target lane (g,li), word w of ks: needs j pair (32ks+8g+2w, +1),
        // which lives at source lane g'*16+li, g' = 2(g&1)+(w>>1),
        // register pk[2ks+(g>>1)][w&1].
        union { uint w[4]; bf16x8 v; } pf[2];
#pragma unroll
        for (int ks = 0; ks < 2; ++ks) {
#pragma unroll
            for (int w = 0; w < 4; ++w) {
                const int src = ((g & 1) << 5) + ((w & 2) << 3) + li;
                const uint a = (uint)__shfl((int)pk[2 * ks + 0][w & 1], src);
                const uint b = (uint)__shfl((int)pk[2 * ks + 1][w & 1], src);
                pf[ks].w[w] = (g & 2) ? b : a;
            }
        }

        // ---- PV: accO[dt] += V^T · P^T (V hi + lo)
#pragma unroll
        for (int dt = 0; dt < 4; ++dt) {
            f32x4 a = accO[dt];
            a = __builtin_amdgcn_mfma_f32_16x16x32_bf16(vfh[dt][0], pf[0].v, a, 0, 0, 0);
            a = __builtin_amdgcn_mfma_f32_16x16x32_bf16(vfl[dt][0], pf[0].v, a, 0, 0, 0);
            a = __builtin_amdgcn_mfma_f32_16x16x32_bf16(vfh[dt][1], pf[1].v, a, 0, 0, 0);
            a = __builtin_amdgcn_mfma_f32_16x16x32_bf16(vfl[dt][1], pf[1].v, a, 0, 0, 0);
            accO[dt] = a;
        }
    }

    // ---- epilogue: O^T[d][i] / l  ->  ao[b][c=d*H+h][n=i]
    const float invl = 1.0f / lrun;
    const int b = bh >> 2;
    const int h = bh & 3;
#pragma unroll
    for (int dt = 0; dt < 4; ++dt)
#pragma unroll
        for (int r = 0; r < 4; ++r) {
            const int d = dt * 16 + 4 * g + r;
            Oo[((size_t)(b * C_ + d * H_ + h)) * N_ + i0 + li] = accO[dt][r] * invl;
        }
}

// ---------------------------------------------------------------------------
extern "C" void kernel_launch(void* const* d_in, const int* in_sizes, int n_in,
                              void* d_out, int out_size, void* d_ws, size_t ws_size,
                              hipStream_t stream) {
    const float* query = (const float*)d_in[0];
    const float* key   = (const float*)d_in[1];
    const float* value = (const float*)d_in[2];
    const float* wq = (const float*)d_in[3];
    const float* bq = (const float*)d_in[4];
    const float* wk = (const float*)d_in[5];
    const float* bk = (const float*)d_in[6];
    const float* wv = (const float*)d_in[7];
    const float* bv = (const float*)d_in[8];
    const float* wm = (const float*)d_in[9];
    const float* bm = (const float*)d_in[10];

    float* out = (float*)d_out;
    float* ws  = (float*)d_ws;

    const size_t TEN = (size_t)B_ * C_ * N_;   // 2,097,152

    float* qp = out;              // q projection scratch (consumed before final GEMM)
    float* kp = ws;               // k projection fp32
    float* ao = ws + TEN;         // attention output fp32
    ushort* ub = (ushort*)(ws + 2 * TEN);
    ushort* Qh = ub;
    ushort* Ql = ub + TEN;
    ushort* Kh = ub + 2 * TEN;
    ushort* Kl = ub + 3 * TEN;
    ushort* Vh = ub + 4 * TEN;
    ushort* Vl = ub + 5 * TEN;
    float* wqT = ws + 5 * TEN;
    float* wkT = wqT + C_ * C_;
    float* wvT = wkT + C_ * C_;
    float* wmT = wvT + C_ * C_;

    dim3 tb(32, 32);
    dim3 tg(8, 8);
    transpose256<<<tg, tb, 0, stream>>>(wq, wqT);
    transpose256<<<tg, tb, 0, stream>>>(wk, wkT);
    transpose256<<<tg, tb, 0, stream>>>(wv, wvT);
    transpose256<<<tg, tb, 0, stream>>>(wm, wmT);

    dim3 gg(N_ / 64, C_ / 64, B_);
    dim3 gb(256);
    conv_gemm<<<gg, gb, 0, stream>>>(wqT, bq, query, qp);
    conv_gemm<<<gg, gb, 0, stream>>>(wkT, bk, key,   kp);
    conv_gemm_v<<<gg, gb, 0, stream>>>(wvT, bv, value, Vh, Vl);

    dim3 rg(N_ / 64, H_, B_);
    repack_qk<<<rg, gb, 0, stream>>>(qp, Qh, Ql, 0.18033688011112042f);  // log2(e)/8
    repack_qk<<<rg, gb, 0, stream>>>(kp, Kh, Kl, 1.0f);

    attn_mfma<<<dim3(512), gb, 0, stream>>>(Qh, Ql, Kh, Kl, Vh, Vl, ao);

    conv_gemm<<<gg, gb, 0, stream>>>(wmT, bm, ao, out);
}

// Round 3
// 137.905 us; speedup vs baseline: 2.7826x; 2.3968x over previous
//
#include <hip/hip_runtime.h>
#include <math.h>

#define B_ 4
#define C_ 256
#define N_ 2048
#define H_ 4
#define D_ 64

typedef __attribute__((ext_vector_type(8))) short bf16x8;
typedef __attribute__((ext_vector_type(4))) float f32x4;

#if __has_builtin(__builtin_amdgcn_exp2f)
#define EXP2(x) __builtin_amdgcn_exp2f(x)
#else
#define EXP2(x) exp2f(x)
#endif

__device__ __forceinline__ ushort f2bf(float x) {
    uint u = __float_as_uint(x);
    uint r = (u + 0x7fffu + ((u >> 16) & 1u)) >> 16;
    return (ushort)r;
}

__device__ __forceinline__ uint4 pack8(const ushort* v) {
    uint4 r;
    r.x = (uint)v[0] | ((uint)v[1] << 16);
    r.y = (uint)v[2] | ((uint)v[3] << 16);
    r.z = (uint)v[4] | ((uint)v[5] << 16);
    r.w = (uint)v[6] | ((uint)v[7] << 16);
    return r;
}

__device__ __forceinline__ void glds16(const ushort* g, ushort* l) {
    __builtin_amdgcn_global_load_lds(
        (const __attribute__((address_space(1))) unsigned int*)g,
        (__attribute__((address_space(3))) unsigned int*)l, 16, 0, 0);
}

// ---------------------------------------------------------------------------
// Weight transpose: Wt[c][o] = W[o][c]  (256x256)
// ---------------------------------------------------------------------------
__global__ __launch_bounds__(1024) void transpose256(const float* __restrict__ W,
                                                     float* __restrict__ Wt) {
    __shared__ float t[32][33];
    const int bx = blockIdx.x * 32, by = blockIdx.y * 32;
    const int x = threadIdx.x, y = threadIdx.y;
    t[y][x] = W[(by + y) * C_ + bx + x];
    __syncthreads();
    Wt[(bx + y) * C_ + by + x] = t[x][y];
}

// ---------------------------------------------------------------------------
// Plain fp32 1x1-conv GEMM (used for the final output projection).
// ---------------------------------------------------------------------------
__global__ __launch_bounds__(256) void conv_gemm(const float* __restrict__ Wt,
                                                 const float* __restrict__ bias,
                                                 const float* __restrict__ X,
                                                 float* __restrict__ Y) {
    const int n0 = blockIdx.x * 64;
    const int o0 = blockIdx.y * 64;
    const int b  = blockIdx.z;
    __shared__ float Ws[32][64];
    __shared__ float Xs[32][64];
    const int tid = threadIdx.x;
    const int tx = tid & 15;
    const int ty = tid >> 4;
    float acc[4][4] = {};
    const float* Xb = X + (size_t)b * C_ * N_;

    for (int kb = 0; kb < C_; kb += 32) {
        __syncthreads();
#pragma unroll
        for (int p = 0; p < 2; ++p) {
            const int idx = tid + p * 256;
            const int k  = idx >> 4;
            const int c4 = (idx & 15) << 2;
            *(float4*)&Ws[k][c4] = *(const float4*)&Wt[(size_t)(kb + k) * C_ + o0 + c4];
            *(float4*)&Xs[k][c4] = *(const float4*)&Xb[(size_t)(kb + k) * N_ + n0 + c4];
        }
        __syncthreads();
#pragma unroll 8
        for (int k = 0; k < 32; ++k) {
            const float4 wv = *(const float4*)&Ws[k][ty << 2];
            const float4 xv = *(const float4*)&Xs[k][tx << 2];
            const float w[4]  = {wv.x, wv.y, wv.z, wv.w};
            const float xr[4] = {xv.x, xv.y, xv.z, xv.w};
#pragma unroll
            for (int i = 0; i < 4; ++i)
#pragma unroll
                for (int j = 0; j < 4; ++j)
                    acc[i][j] += w[i] * xr[j];
        }
    }
#pragma unroll
    for (int i = 0; i < 4; ++i) {
        const int o = o0 + (ty << 2) + i;
        const float bo = bias[o];
        float4 r;
        r.x = acc[i][0] + bo; r.y = acc[i][1] + bo;
        r.z = acc[i][2] + bo; r.w = acc[i][3] + bo;
        *(float4*)&Y[((size_t)b * C_ + o) * N_ + n0 + (tx << 2)] = r;
    }
}

// ---------------------------------------------------------------------------
// Fused projection: fp32 GEMM (identical math to conv_gemm) + bf16 repack.
// MODE 0: Q -> Qb[bh][n][64] bf16 (scale folded: log2(e)/8)
// MODE 1: K -> Kimg[bh][kt][4096] swizzled tile image: idx = j*64 + (d ^ ((j&7)<<3))
// MODE 2: V -> Vimg[bh][kt][4096] swizzled tile image: idx = d*64 + (j ^ ((d&7)<<3))
// channel o = d*H + h.
// ---------------------------------------------------------------------------
template <int MODE>
__global__ __launch_bounds__(256) void conv_pack(const float* __restrict__ Wt,
                                                 const float* __restrict__ bias,
                                                 const float* __restrict__ X,
                                                 ushort* __restrict__ Dst,
                                                 float scale) {
    const int n0 = blockIdx.x * 64;
    const int o0 = blockIdx.y * 64;
    const int b  = blockIdx.z;
    __shared__ float Ws[32][64];
    __shared__ float Xs[32][64];
    __shared__ ushort Ls[64][68];   // [n][o], padded stride
    const int tid = threadIdx.x;
    const int tx = tid & 15;
    const int ty = tid >> 4;
    float acc[4][4] = {};
    const float* Xb = X + (size_t)b * C_ * N_;

    for (int kb = 0; kb < C_; kb += 32) {
        __syncthreads();
#pragma unroll
        for (int p = 0; p < 2; ++p) {
            const int idx = tid + p * 256;
            const int k  = idx >> 4;
            const int c4 = (idx & 15) << 2;
            *(float4*)&Ws[k][c4] = *(const float4*)&Wt[(size_t)(kb + k) * C_ + o0 + c4];
            *(float4*)&Xs[k][c4] = *(const float4*)&Xb[(size_t)(kb + k) * N_ + n0 + c4];
        }
        __syncthreads();
#pragma unroll 8
        for (int k = 0; k < 32; ++k) {
            const float4 wv = *(const float4*)&Ws[k][ty << 2];
            const float4 xv = *(const float4*)&Xs[k][tx << 2];
            const float w[4]  = {wv.x, wv.y, wv.z, wv.w};
            const float xr[4] = {xv.x, xv.y, xv.z, xv.w};
#pragma unroll
            for (int i = 0; i < 4; ++i)
#pragma unroll
                for (int j = 0; j < 4; ++j)
                    acc[i][j] += w[i] * xr[j];
        }
    }

    // ---- stage bf16 tile to LDS: Ls[n][o]
#pragma unroll
    for (int j = 0; j < 4; ++j) {
        ushort u[4];
#pragma unroll
        for (int i = 0; i < 4; ++i) {
            const int o = o0 + (ty << 2) + i;
            u[i] = f2bf((acc[i][j] + bias[o]) * scale);
        }
        *(uint2*)&Ls[(tx << 2) + j][ty << 2] =
            make_uint2((uint)u[0] | ((uint)u[1] << 16), (uint)u[2] | ((uint)u[3] << 16));
    }
    __syncthreads();

    const int d0 = o0 >> 2;
    const int kt = n0 >> 6;

    if (MODE == 0) {
        const int h = tid >> 6, n = tid & 63;
        ushort vals[16];
#pragma unroll
        for (int dd = 0; dd < 16; ++dd) vals[dd] = Ls[n][h + (dd << 2)];
        ushort* dst = Dst + ((size_t)((b * H_ + h) * N_) + n0 + n) * 64 + d0;
        *(uint4*)dst       = pack8(vals);
        *(uint4*)(dst + 8) = pack8(vals + 8);
    } else if (MODE == 1) {
        const int h = tid >> 6, j = tid & 63;
        ushort vals[16];
#pragma unroll
        for (int dd = 0; dd < 16; ++dd) vals[dd] = Ls[j][h + (dd << 2)];
        const int x = (j & 7) << 3;
        ushort* base = Dst + (((size_t)(b * H_ + h) * 32 + kt) << 12) + j * 64 + (d0 ^ (x & 48));
        const int fl = x & 8;
#pragma unroll
        for (int q = 0; q < 2; ++q)
            *(uint4*)(base + q * 8) = pack8(vals + ((q * 8) ^ fl));
    } else {
        const int h = tid >> 6, rem = tid & 63;
        const int dd = rem >> 2, jq = rem & 3;
        const int o = h + (dd << 2);
        ushort vals[16];
#pragma unroll
        for (int jj = 0; jj < 16; ++jj) vals[jj] = Ls[(jq << 4) + jj][o];
        const int d = d0 + dd;
        const int x = (d & 7) << 3;
        ushort* base = Dst + (((size_t)(b * H_ + h) * 32 + kt) << 12) + d * 64 + ((jq << 4) ^ (x & 48));
        const int fl = x & 8;
#pragma unroll
        for (int q = 0; q < 2; ++q)
            *(uint4*)(base + q * 8) = pack8(vals + ((q * 8) ^ fl));
    }
}

// ---------------------------------------------------------------------------
// bf16 MFMA flash attention, max-free softmax (scores provably bounded).
// Block = 4 waves, 128 queries (32/wave, 2 q-groups of 16). K-tile = 64 keys.
// K/V tile images staged global->LDS via global_load_lds, double-buffered.
// S^T = mfma(A=K, B=Q); P routed through wave-private swizzled LDS;
// O^T = mfma(A=V^T, B=P^T). l-reduction once at the end.
// ---------------------------------------------------------------------------
__global__ __launch_bounds__(256) void attn_v3(const ushort* __restrict__ Qb,
                                               const ushort* __restrict__ Kimg,
                                               const ushort* __restrict__ Vimg,
                                               float* __restrict__ Oo) {
    __shared__ ushort SMEM[24576];   // KT dbuf 16KB | VT dbuf 16KB | P 16KB

    const int bid = blockIdx.x;
    const int L  = (bid & 7) * 32 + (bid >> 3);   // XCD swizzle (bijective, 256 blocks)
    const int bh = L >> 4;
    const int qt = L & 15;

    const int tid  = threadIdx.x;
    const int wv   = tid >> 6;
    const int lane = tid & 63;
    const int li   = lane & 15;
    const int g    = lane >> 4;
    const int l7   = li & 7;
    const int i0w  = qt * 128 + wv * 32;

    // ---- Q fragments (resident whole kernel)
    bf16x8 qf[2][2];
#pragma unroll
    for (int qg = 0; qg < 2; ++qg)
#pragma unroll
        for (int ks = 0; ks < 2; ++ks)
            qf[qg][ks] = *(const bf16x8*)(Qb + ((size_t)bh * N_ + i0w + qg * 16 + li) * 64 +
                                          ks * 32 + g * 8);

    const ushort* Kg = Kimg + ((size_t)bh * 32 << 12);
    const ushort* Vg = Vimg + ((size_t)bh * 32 << 12);
    ushort* Pw = SMEM + 16384 + wv * 2048;

    const f32x4 z = {0.f, 0.f, 0.f, 0.f};
    f32x4 accO[4][2] = {{z, z}, {z, z}, {z, z}, {z, z}};
    float lsum[2] = {0.f, 0.f};

#define STAGE(buf, kt_)                                                              \
    do {                                                                             \
        const int off0 = wv * 1024;                                                  \
        const ushort* ksrc = Kg + ((kt_) << 12) + off0 + lane * 8;                   \
        const ushort* vsrc = Vg + ((kt_) << 12) + off0 + lane * 8;                   \
        glds16(ksrc,        SMEM + (buf) * 4096 + off0);                             \
        glds16(ksrc + 512,  SMEM + (buf) * 4096 + off0 + 512);                       \
        glds16(vsrc,        SMEM + 8192 + (buf) * 4096 + off0);                      \
        glds16(vsrc + 512,  SMEM + 8192 + (buf) * 4096 + off0 + 512);                \
    } while (0)

    STAGE(0, 0);
    __syncthreads();

    int cur = 0;
    for (int kt = 0; kt < 32; ++kt) {
        if (kt + 1 < 32) STAGE(cur ^ 1, kt + 1);

        const ushort* Kc = SMEM + cur * 4096;
        const ushort* Vc = SMEM + 8192 + cur * 4096;

        // ---- QK^T (S^T[j][q]); lane holds j = 16jt+4g+r, q = qg*16+li
        f32x4 s[4][2];
#pragma unroll
        for (int jt = 0; jt < 4; ++jt) {
            const ushort* row = Kc + (16 * jt + li) * 64;
            const bf16x8 kf0 = *(const bf16x8*)(row + 8 * (g ^ l7));
            const bf16x8 kf1 = *(const bf16x8*)(row + 8 * ((4 + g) ^ l7));
#pragma unroll
            for (int qg = 0; qg < 2; ++qg) {
                f32x4 a = z;
                a = __builtin_amdgcn_mfma_f32_16x16x32_bf16(kf0, qf[qg][0], a, 0, 0, 0);
                a = __builtin_amdgcn_mfma_f32_16x16x32_bf16(kf1, qf[qg][1], a, 0, 0, 0);
                s[jt][qg] = a;
            }
        }

        // ---- max-free softmax: p = exp2(s); accumulate l; write P^T to LDS
#pragma unroll
        for (int qg = 0; qg < 2; ++qg) {
            const uint rowb = (qg * 16 + li) * 128;
#pragma unroll
            for (int jt = 0; jt < 4; ++jt) {
                const float p0 = EXP2(s[jt][qg][0]);
                const float p1 = EXP2(s[jt][qg][1]);
                const float p2 = EXP2(s[jt][qg][2]);
                const float p3 = EXP2(s[jt][qg][3]);
                lsum[qg] += (p0 + p1) + (p2 + p3);
                const uint a01 = (__float_as_uint(p1) & 0xffff0000u) | (__float_as_uint(p0) >> 16);
                const uint a23 = (__float_as_uint(p3) & 0xffff0000u) | (__float_as_uint(p2) >> 16);
                const uint byteoff = rowb + ((uint)(jt * 32 + g * 8) ^ (uint)(l7 << 4));
                *(uint2*)((char*)Pw + byteoff) = make_uint2(a01, a23);
            }
        }

        // ---- P^T fragments back from LDS
        bf16x8 pf[2][2];
#pragma unroll
        for (int qg = 0; qg < 2; ++qg)
#pragma unroll
            for (int ks = 0; ks < 2; ++ks)
                pf[qg][ks] = *(const bf16x8*)((char*)Pw + (qg * 16 + li) * 128 +
                                              16 * ((4 * ks + g) ^ l7));

        // ---- PV: accO[dt][qg] += V^T . P^T
#pragma unroll
        for (int dt = 0; dt < 4; ++dt) {
            const ushort* row = Vc + (16 * dt + li) * 64;
            const bf16x8 vf0 = *(const bf16x8*)(row + 8 * (g ^ l7));
            const bf16x8 vf1 = *(const bf16x8*)(row + 8 * ((4 + g) ^ l7));
#pragma unroll
            for (int qg = 0; qg < 2; ++qg) {
                f32x4 a = accO[dt][qg];
                a = __builtin_amdgcn_mfma_f32_16x16x32_bf16(vf0, pf[qg][0], a, 0, 0, 0);
                a = __builtin_amdgcn_mfma_f32_16x16x32_bf16(vf1, pf[qg][1], a, 0, 0, 0);
                accO[dt][qg] = a;
            }
        }

        __syncthreads();
        cur ^= 1;
    }

    // ---- l reduction across g-groups (lanes sharing li hold same q)
    float invl[2];
#pragma unroll
    for (int qg = 0; qg < 2; ++qg) {
        float l = lsum[qg];
        l += __shfl_xor(l, 16);
        l += __shfl_xor(l, 32);
        invl[qg] = 1.0f / l;
    }

    __syncthreads();   // done with K/V buffers; reuse as fp32 O staging
    char* Of = (char*)SMEM + wv * 8192;   // 64d x 32q fp32, swizzled

#pragma unroll
    for (int dt = 0; dt < 4; ++dt)
#pragma unroll
        for (int qg = 0; qg < 2; ++qg)
#pragma unroll
            for (int r = 0; r < 4; ++r) {
                const int d = 16 * dt + 4 * g + r;
                const int q = qg * 16 + li;
                *(float*)(Of + (d * 128 + ((q * 4) ^ ((d & 7) << 4)))) =
                    accO[dt][qg][r] * invl[qg];
            }

    const int b = bh >> 2, h = bh & 3;
#pragma unroll
    for (int it = 0; it < 8; ++it) {
        const int d  = it * 8 + (lane >> 3);
        const int q4 = lane & 7;
        const f32x4 v = *(const f32x4*)(Of + d * 128 + 16 * (q4 ^ (d & 7)));
        *(f32x4*)&Oo[((size_t)(b * C_ + d * H_ + h)) * N_ + i0w + q4 * 4] = v;
    }
}

// ---------------------------------------------------------------------------
extern "C" void kernel_launch(void* const* d_in, const int* in_sizes, int n_in,
                              void* d_out, int out_size, void* d_ws, size_t ws_size,
                              hipStream_t stream) {
    const float* query = (const float*)d_in[0];
    const float* key   = (const float*)d_in[1];
    const float* value = (const float*)d_in[2];
    const float* wq = (const float*)d_in[3];
    const float* bq = (const float*)d_in[4];
    const float* wk = (const float*)d_in[5];
    const float* bk = (const float*)d_in[6];
    const float* wv = (const float*)d_in[7];
    const float* bv = (const float*)d_in[8];
    const float* wm = (const float*)d_in[9];
    const float* bm = (const float*)d_in[10];

    float* out = (float*)d_out;
    float* ws  = (float*)d_ws;

    const size_t TEN = (size_t)B_ * C_ * N_;   // 2,097,152

    float*  ao   = ws;                         // attention output fp32
    ushort* Qb   = (ushort*)(ws + TEN);        // 2M ushorts
    ushort* Kimg = Qb + TEN;
    ushort* Vimg = Kimg + TEN;
    float*  wqT  = (float*)(Vimg + TEN);
    float*  wkT  = wqT + C_ * C_;
    float*  wvT  = wkT + C_ * C_;
    float*  wmT  = wvT + C_ * C_;

    dim3 tb(32, 32);
    dim3 tg(8, 8);
    transpose256<<<tg, tb, 0, stream>>>(wq, wqT);
    transpose256<<<tg, tb, 0, stream>>>(wk, wkT);
    transpose256<<<tg, tb, 0, stream>>>(wv, wvT);
    transpose256<<<tg, tb, 0, stream>>>(wm, wmT);

    dim3 gg(N_ / 64, C_ / 64, B_);
    dim3 gb(256);
    const float qscale = 0.18033688011112042f;   // log2(e)/8
    conv_pack<0><<<gg, gb, 0, stream>>>(wqT, bq, query, Qb,   qscale);
    conv_pack<1><<<gg, gb, 0, stream>>>(wkT, bk, key,   Kimg, 1.0f);
    conv_pack<2><<<gg, gb, 0, stream>>>(wvT, bv, value, Vimg, 1.0f);

    attn_v3<<<dim3(256), gb, 0, stream>>>(Qb, Kimg, Vimg, ao);

    conv_gemm<<<gg, gb, 0, stream>>>(wmT, bm, ao, out);
}

// Round 4
// 94.308 us; speedup vs baseline: 4.0689x; 1.4623x over previous
//
#include <hip/hip_runtime.h>
#include <math.h>

#define B_ 4
#define C_ 256
#define N_ 2048
#define H_ 4
#define D_ 64

typedef __attribute__((ext_vector_type(8))) short bf16x8;
typedef __attribute__((ext_vector_type(4))) float f32x4;

#define EXP2(x) exp2f(x)
#define QSCALE 0.18033688011112042f   // log2(e)/8

__device__ __forceinline__ ushort f2bf(float x) {
    uint u = __float_as_uint(x);
    uint r = (u + 0x7fffu + ((u >> 16) & 1u)) >> 16;
    return (ushort)r;
}
__device__ __forceinline__ float bf2f(ushort u) {
    return __uint_as_float((uint)u << 16);
}
__device__ __forceinline__ uint4 pack8(const ushort* v) {
    uint4 r;
    r.x = (uint)v[0] | ((uint)v[1] << 16);
    r.y = (uint)v[2] | ((uint)v[3] << 16);
    r.z = (uint)v[4] | ((uint)v[5] << 16);
    r.w = (uint)v[6] | ((uint)v[7] << 16);
    return r;
}
__device__ __forceinline__ void glds16(const ushort* g, ushort* l) {
    __builtin_amdgcn_global_load_lds(
        (const __attribute__((address_space(1))) unsigned int*)g,
        (__attribute__((address_space(3))) unsigned int*)l, 16, 0, 0);
}

// ---------------------------------------------------------------------------
// pack_w: W fp32 [o][c] -> hi/lo bf16 MFMA A-fragment images.
// Whimg[wsel][ (ks*16+of)*64 + lane ][8]: lane l holds W[of*16+(l&15)][32ks+(l>>4)*8+e]
// ---------------------------------------------------------------------------
__global__ __launch_bounds__(256) void pack_w(const float* __restrict__ w0,
                                              const float* __restrict__ w1,
                                              const float* __restrict__ w2,
                                              const float* __restrict__ w3,
                                              ushort* __restrict__ Whimg,
                                              ushort* __restrict__ Wlimg) {
    const int ws = blockIdx.x;
    const float* W = ws == 0 ? w0 : ws == 1 ? w1 : ws == 2 ? w2 : w3;
    ushort* Hh = Whimg + ws * 65536;
    ushort* Hl = Wlimg + ws * 65536;
    const int o  = threadIdx.x;
    const int of = o >> 4;
    const int li = o & 15;
#pragma unroll
    for (int ks = 0; ks < 8; ++ks) {
#pragma unroll
        for (int g = 0; g < 4; ++g) {
            float v[8];
            *(float4*)&v[0] = *(const float4*)&W[o * 256 + ks * 32 + g * 8];
            *(float4*)&v[4] = *(const float4*)&W[o * 256 + ks * 32 + g * 8 + 4];
            ushort hi[8], lo[8];
#pragma unroll
            for (int e = 0; e < 8; ++e) {
                hi[e] = f2bf(v[e]);
                lo[e] = f2bf(v[e] - bf2f(hi[e]));
            }
            const size_t dst = ((size_t)(ks * 16 + of) * 64 + (g * 16 + li)) * 8;
            *(uint4*)(Hh + dst) = pack8(hi);
            *(uint4*)(Hl + dst) = pack8(lo);
        }
    }
}

// ---------------------------------------------------------------------------
// pack_x: fp32 X[b][c][n] -> bf16 granule-swizzled B-tile images.
// Image per (z = sel*4+b, nt(32n), ks(32c)): 128 granules of 8 bf16 (along c).
// Logical granule G = (n&31)*4 + (c&31)/8 stored at slot G ^ (n&7).
// ---------------------------------------------------------------------------
__global__ __launch_bounds__(256) void pack_x(const float* __restrict__ q,
                                              const float* __restrict__ k,
                                              const float* __restrict__ v,
                                              ushort* __restrict__ Ximg) {
    const int z   = blockIdx.z;            // sel*4 + b
    const int sel = z >> 2, b = z & 3;
    const int n0  = blockIdx.x * 64;
    const int ks  = blockIdx.y;            // 0..7
    const float* X = (sel == 0 ? q : sel == 1 ? k : v) + (size_t)b * C_ * N_;
    const int t   = threadIdx.x;
    const int n_l = t & 63;
    const int g   = t >> 6;
    const int c0  = ks * 32 + g * 8;
    ushort u[8];
#pragma unroll
    for (int e = 0; e < 8; ++e)
        u[e] = f2bf(X[(size_t)(c0 + e) * N_ + n0 + n_l]);
    const int nt = (n0 >> 5) + (n_l >> 5);
    const int nl = n_l & 31;
    const int G  = nl * 4 + g;
    const int Gp = G ^ (nl & 7);
    ushort* dst = Ximg + ((((size_t)z * 64 + nt) * 8 + ks) * 128 + Gp) * 8;
    *(uint4*)dst = pack8(u);
}

// ---------------------------------------------------------------------------
// proj_mfma: Y[o][n] = bias[o] + sum_c W[o][c] X[c][n], bf16 MFMA, W hi/lo
// 2-product. Block: 256c(out) x 32n, 4 waves split on o. B-tile staged via
// global_load_lds from pre-swizzled images, double-buffered.
// Epilogue packs to Qb / Kimg / Vimg (attention-ready layouts).
// ---------------------------------------------------------------------------
__global__ __launch_bounds__(256) void proj_mfma(const ushort* __restrict__ Ximg,
                                                 const ushort* __restrict__ Whimg,
                                                 const ushort* __restrict__ Wlimg,
                                                 const float* __restrict__ bq,
                                                 const float* __restrict__ bk,
                                                 const float* __restrict__ bv,
                                                 ushort* __restrict__ Qb,
                                                 ushort* __restrict__ Kimg,
                                                 ushort* __restrict__ Vimg) {
    __shared__ ushort Bt[2][1024];
    __shared__ ushort Ls[32][264];

    const int z   = blockIdx.z;           // sel*4+b
    const int sel = z >> 2, b = z & 3;
    const int nt  = blockIdx.x;           // 0..63 (n0 = nt*32)
    const int tid  = threadIdx.x;
    const int wv   = tid >> 6;
    const int lane = tid & 63;
    const int li   = lane & 15;
    const int g    = lane >> 4;

    const ushort* img = Ximg + (((size_t)z * 64 + nt) * 8) * 1024;
    const ushort* Wh  = Whimg + sel * 65536;
    const ushort* Wl  = Wlimg + sel * 65536;
    const float* bias = sel == 0 ? bq : sel == 1 ? bk : bv;

    const f32x4 zv = {0.f, 0.f, 0.f, 0.f};
    f32x4 acc[4][2] = {{zv, zv}, {zv, zv}, {zv, zv}, {zv, zv}};

    if (tid < 128)
        glds16(img + (size_t)tid * 8, (ushort*)Bt[0] + (tid >> 6) * 512);
    __syncthreads();

    int cur = 0;
    for (int ks = 0; ks < 8; ++ks) {
        if (ks < 7 && tid < 128)
            glds16(img + (size_t)(ks + 1) * 1024 + (size_t)tid * 8,
                   (ushort*)Bt[cur ^ 1] + (tid >> 6) * 512);

        bf16x8 bf[2];
#pragma unroll
        for (int nf = 0; nf < 2; ++nf) {
            const int G  = (16 * nf + li) * 4 + g;
            const int Gp = G ^ (li & 7);
            bf[nf] = *(const bf16x8*)((const ushort*)Bt[cur] + Gp * 8);
        }
        const size_t abase = ((size_t)(ks * 16 + wv * 4) * 64 + lane) * 8;
#pragma unroll
        for (int ot = 0; ot < 4; ++ot) {
            const bf16x8 ah = *(const bf16x8*)(Wh + abase + (size_t)ot * 512);
            const bf16x8 al = *(const bf16x8*)(Wl + abase + (size_t)ot * 512);
#pragma unroll
            for (int nf = 0; nf < 2; ++nf) {
                f32x4 a = acc[ot][nf];
                a = __builtin_amdgcn_mfma_f32_16x16x32_bf16(al, bf[nf], a, 0, 0, 0);
                a = __builtin_amdgcn_mfma_f32_16x16x32_bf16(ah, bf[nf], a, 0, 0, 0);
                acc[ot][nf] = a;
            }
        }
        __syncthreads();
        cur ^= 1;
    }

    // ---- epilogue: bias (+scale for Q), stage bf16 tile Ls[n][o]
    const float scale = (sel == 0) ? QSCALE : 1.0f;
#pragma unroll
    for (int ot = 0; ot < 4; ++ot)
#pragma unroll
        for (int nf = 0; nf < 2; ++nf)
#pragma unroll
            for (int r = 0; r < 4; ++r) {
                const int o = wv * 64 + ot * 16 + g * 4 + r;
                Ls[nf * 16 + li][o] = f2bf((acc[ot][nf][r] + bias[o]) * scale);
            }
    __syncthreads();

    const int h  = tid >> 6;
    const int bh = b * 4 + h;
    if (sel == 0) {
#pragma unroll
        for (int r_ = 0; r_ < 4; ++r_) {
            const int gi = (tid & 63) + 64 * r_;
            const int n_l = gi >> 3, dr = gi & 7;
            ushort u[8];
#pragma unroll
            for (int e = 0; e < 8; ++e) u[e] = Ls[n_l][(dr * 8 + e) * 4 + h];
            *(uint4*)(Qb + (((size_t)bh * N_) + nt * 32 + n_l) * 64 + dr * 8) = pack8(u);
        }
    } else if (sel == 1) {
#pragma unroll
        for (int r_ = 0; r_ < 4; ++r_) {
            const int gi = (tid & 63) + 64 * r_;
            const int n_l = gi >> 3, dr = gi & 7;
            ushort u[8];
#pragma unroll
            for (int e = 0; e < 8; ++e) u[e] = Ls[n_l][(dr * 8 + e) * 4 + h];
            const int jg    = nt * 32 + n_l;
            const int j     = jg & 63;
            const int ktile = jg >> 6;
            *(uint4*)(Kimg + (((size_t)bh * 32 + ktile) << 12) + j * 64 +
                      ((dr * 8) ^ ((j & 7) << 3))) = pack8(u);
        }
    } else {
#pragma unroll
        for (int r_ = 0; r_ < 4; ++r_) {
            const int gi = (tid & 63) + 64 * r_;
            const int d = gi >> 2, jr = gi & 3;
            ushort u[8];
#pragma unroll
            for (int e = 0; e < 8; ++e) u[e] = Ls[jr * 8 + e][d * 4 + h];
            const int jbase = (nt & 1) * 32 + jr * 8;
            const int ktile = nt >> 1;
            *(uint4*)(Vimg + (((size_t)bh * 32 + ktile) << 12) + d * 64 +
                      (jbase ^ ((d & 7) << 3))) = pack8(u);
        }
    }
}

// ---------------------------------------------------------------------------
// attn_v4: split-K flash attention (max-free softmax). 512 blocks =
// 2 splits x 16 bh x 16 q-tiles; each block does 16 K-tiles of 64.
// Writes UNNORMALIZED partial O^T (f32) and partial l.
// ---------------------------------------------------------------------------
__global__ __launch_bounds__(256) void attn_v4(const ushort* __restrict__ Qb,
                                               const ushort* __restrict__ Kimg,
                                               const ushort* __restrict__ Vimg,
                                               float* __restrict__ Opart,
                                               float* __restrict__ lpart) {
    __shared__ ushort SMEM[24576];   // KT dbuf 16KB | VT dbuf 16KB | P 16KB

    const int i    = blockIdx.x;
    const int xcd  = i & 7;
    const int slot = i >> 3;
    const int qt   = slot & 15;
    const int Gg   = (slot >> 4) * 8 + xcd;   // 0..31
    const int s    = Gg >> 4;
    const int bh   = Gg & 15;

    const int tid  = threadIdx.x;
    const int wv   = tid >> 6;
    const int lane = tid & 63;
    const int li   = lane & 15;
    const int g    = lane >> 4;
    const int l7   = li & 7;
    const int i0w  = qt * 128 + wv * 32;

    bf16x8 qf[2][2];
#pragma unroll
    for (int qg = 0; qg < 2; ++qg)
#pragma unroll
        for (int ks = 0; ks < 2; ++ks)
            qf[qg][ks] = *(const bf16x8*)(Qb + ((size_t)bh * N_ + i0w + qg * 16 + li) * 64 +
                                          ks * 32 + g * 8);

    const ushort* Kg = Kimg + ((size_t)bh * 32 << 12);
    const ushort* Vg = Vimg + ((size_t)bh * 32 << 12);
    ushort* Pw = SMEM + 16384 + wv * 2048;

    const f32x4 z = {0.f, 0.f, 0.f, 0.f};
    f32x4 accO[4][2] = {{z, z}, {z, z}, {z, z}, {z, z}};
    float lsum[2] = {0.f, 0.f};

#define STAGE(buf, kt_)                                                              \
    do {                                                                             \
        const int off0 = wv * 1024;                                                  \
        const ushort* ksrc = Kg + ((size_t)(kt_) << 12) + off0 + lane * 8;           \
        const ushort* vsrc = Vg + ((size_t)(kt_) << 12) + off0 + lane * 8;           \
        glds16(ksrc,        SMEM + (buf) * 4096 + off0);                             \
        glds16(ksrc + 512,  SMEM + (buf) * 4096 + off0 + 512);                       \
        glds16(vsrc,        SMEM + 8192 + (buf) * 4096 + off0);                      \
        glds16(vsrc + 512,  SMEM + 8192 + (buf) * 4096 + off0 + 512);                \
    } while (0)

    const int kt0 = s * 16, kt1 = kt0 + 16;
    STAGE(0, kt0);
    __syncthreads();

    int cur = 0;
    for (int kt = kt0; kt < kt1; ++kt) {
        if (kt + 1 < kt1) STAGE(cur ^ 1, kt + 1);

        const ushort* Kc = SMEM + cur * 4096;
        const ushort* Vc = SMEM + 8192 + cur * 4096;

        f32x4 sc[4][2];
#pragma unroll
        for (int jt = 0; jt < 4; ++jt) {
            const ushort* row = Kc + (16 * jt + li) * 64;
            const bf16x8 kf0 = *(const bf16x8*)(row + 8 * (g ^ l7));
            const bf16x8 kf1 = *(const bf16x8*)(row + 8 * ((4 + g) ^ l7));
#pragma unroll
            for (int qg = 0; qg < 2; ++qg) {
                f32x4 a = z;
                a = __builtin_amdgcn_mfma_f32_16x16x32_bf16(kf0, qf[qg][0], a, 0, 0, 0);
                a = __builtin_amdgcn_mfma_f32_16x16x32_bf16(kf1, qf[qg][1], a, 0, 0, 0);
                sc[jt][qg] = a;
            }
        }

#pragma unroll
        for (int qg = 0; qg < 2; ++qg) {
            const uint rowb = (qg * 16 + li) * 128;
#pragma unroll
            for (int jt = 0; jt < 4; ++jt) {
                const float p0 = EXP2(sc[jt][qg][0]);
                const float p1 = EXP2(sc[jt][qg][1]);
                const float p2 = EXP2(sc[jt][qg][2]);
                const float p3 = EXP2(sc[jt][qg][3]);
                lsum[qg] += (p0 + p1) + (p2 + p3);
                const uint a01 = (__float_as_uint(p1) & 0xffff0000u) | (__float_as_uint(p0) >> 16);
                const uint a23 = (__float_as_uint(p3) & 0xffff0000u) | (__float_as_uint(p2) >> 16);
                const uint byteoff = rowb + ((uint)(jt * 32 + g * 8) ^ (uint)(l7 << 4));
                *(uint2*)((char*)Pw + byteoff) = make_uint2(a01, a23);
            }
        }

        bf16x8 pf[2][2];
#pragma unroll
        for (int qg = 0; qg < 2; ++qg)
#pragma unroll
            for (int ks = 0; ks < 2; ++ks)
                pf[qg][ks] = *(const bf16x8*)((char*)Pw + (qg * 16 + li) * 128 +
                                              16 * ((4 * ks + g) ^ l7));

#pragma unroll
        for (int dt = 0; dt < 4; ++dt) {
            const ushort* row = Vc + (16 * dt + li) * 64;
            const bf16x8 vf0 = *(const bf16x8*)(row + 8 * (g ^ l7));
            const bf16x8 vf1 = *(const bf16x8*)(row + 8 * ((4 + g) ^ l7));
#pragma unroll
            for (int qg = 0; qg < 2; ++qg) {
                f32x4 a = accO[dt][qg];
                a = __builtin_amdgcn_mfma_f32_16x16x32_bf16(vf0, pf[qg][0], a, 0, 0, 0);
                a = __builtin_amdgcn_mfma_f32_16x16x32_bf16(vf1, pf[qg][1], a, 0, 0, 0);
                accO[dt][qg] = a;
            }
        }

        __syncthreads();
        cur ^= 1;
    }

    float lt[2];
#pragma unroll
    for (int qg = 0; qg < 2; ++qg) {
        float l = lsum[qg];
        l += __shfl_xor(l, 16);
        l += __shfl_xor(l, 32);
        lt[qg] = l;
    }

    __syncthreads();   // reuse K/V buffers as fp32 O staging
    char* Of = (char*)SMEM + wv * 8192;
#pragma unroll
    for (int dt = 0; dt < 4; ++dt)
#pragma unroll
        for (int qg = 0; qg < 2; ++qg)
#pragma unroll
            for (int r = 0; r < 4; ++r) {
                const int d = 16 * dt + 4 * g + r;
                const int q = qg * 16 + li;
                *(float*)(Of + (d * 128 + ((q * 4) ^ ((d & 7) << 4)))) = accO[dt][qg][r];
            }
    __syncthreads();

    const size_t tbase = (size_t)(s * 256 + (bh << 4) + qt);
    float* Op = Opart + tbase * 8192;
#pragma unroll
    for (int it = 0; it < 8; ++it) {
        const int d  = it * 8 + (lane >> 3);
        const int q4 = lane & 7;
        const f32x4 v = *(const f32x4*)(Of + d * 128 + 16 * (q4 ^ (d & 7)));
        *(f32x4*)&Op[d * 128 + wv * 32 + q4 * 4] = v;
    }
    if (g == 0) {
        lpart[tbase * 128 + wv * 32 + li]      = lt[0];
        lpart[tbase * 128 + wv * 32 + 16 + li] = lt[1];
    }
}

// ---------------------------------------------------------------------------
// conv_out: fused split-combine + output projection (bf16 MFMA, 3-product).
// Block: 256o x 16n. Combines Opart splits, divides by l, stages hi/lo bf16
// B-tile in LDS (granule-swizzled), runs 8 k-steps, writes fp32 out.
// ---------------------------------------------------------------------------
__global__ __launch_bounds__(256) void conv_out(const float* __restrict__ Opart,
                                                const float* __restrict__ lpart,
                                                const ushort* __restrict__ Whimg,
                                                const ushort* __restrict__ Wlimg,
                                                const float* __restrict__ bm,
                                                float* __restrict__ out) {
    __shared__ ushort Bh[512 * 8];
    __shared__ ushort Bl[512 * 8];
    __shared__ float Linv[4][16];

    const int bx  = blockIdx.x;        // 0..127
    const int b   = blockIdx.y;        // 0..3
    const int n0  = bx * 16;
    const int qt  = n0 >> 7;
    const int ql0 = n0 & 127;
    const int tid = threadIdx.x;

    if (tid < 64) {
        const int h = tid >> 4, q = tid & 15;
        const size_t tile = (size_t)(((b * 4 + h) << 4) | qt);
        const float l0 = lpart[tile * 128 + ql0 + q];
        const float l1 = lpart[(256 + tile) * 128 + ql0 + q];
        Linv[h][q] = 1.0f / (l0 + l1);
    }
    __syncthreads();

#pragma unroll
    for (int it = 0; it < 8; ++it) {
        const int id = tid + 256 * it;        // 0..2047
        const int q4 = id & 3;
        const int d  = (id >> 2) & 63;
        const int h  = id >> 9;
        const size_t tile = (size_t)(((b * 4 + h) << 4) | qt);
        const size_t off  = (tile * 64 + d) * 128 + ql0 + q4 * 4;
        const f32x4 v0 = *(const f32x4*)&Opart[off];
        const f32x4 v1 = *(const f32x4*)&Opart[(size_t)256 * 8192 + off];
        const int cg = d >> 1;
        const int eb = (d & 1) * 4 + h;
#pragma unroll
        for (int e = 0; e < 4; ++e) {
            const int q = q4 * 4 + e;
            const float vv = (v0[e] + v1[e]) * Linv[h][q];
            const ushort hi = f2bf(vv);
            const ushort lo = f2bf(vv - bf2f(hi));
            const int Gp = (q * 32 + cg) ^ (q & 7);
            Bh[Gp * 8 + eb] = hi;
            Bl[Gp * 8 + eb] = lo;
        }
    }
    __syncthreads();

    const int wv = tid >> 6, lane = tid & 63, li = lane & 15, g = lane >> 4;
    const ushort* Wh = Whimg + 3 * 65536;
    const ushort* Wl = Wlimg + 3 * 65536;
    const f32x4 zv = {0.f, 0.f, 0.f, 0.f};
    f32x4 acc[4] = {zv, zv, zv, zv};

    for (int ks = 0; ks < 8; ++ks) {
        const int Gp = (li * 32 + ks * 4 + g) ^ (li & 7);
        const bf16x8 bh_ = *(const bf16x8*)(Bh + Gp * 8);
        const bf16x8 bl_ = *(const bf16x8*)(Bl + Gp * 8);
        const size_t abase = ((size_t)(ks * 16 + wv * 4) * 64 + lane) * 8;
#pragma unroll
        for (int ot = 0; ot < 4; ++ot) {
            const bf16x8 ah = *(const bf16x8*)(Wh + abase + (size_t)ot * 512);
            const bf16x8 al = *(const bf16x8*)(Wl + abase + (size_t)ot * 512);
            f32x4 a = acc[ot];
            a = __builtin_amdgcn_mfma_f32_16x16x32_bf16(ah, bl_, a, 0, 0, 0);
            a = __builtin_amdgcn_mfma_f32_16x16x32_bf16(al, bh_, a, 0, 0, 0);
            a = __builtin_amdgcn_mfma_f32_16x16x32_bf16(ah, bh_, a, 0, 0, 0);
            acc[ot] = a;
        }
    }

#pragma unroll
    for (int ot = 0; ot < 4; ++ot)
#pragma unroll
        for (int r = 0; r < 4; ++r) {
            const int o = wv * 64 + ot * 16 + g * 4 + r;
            out[((size_t)(b * 256 + o)) * N_ + n0 + li] = acc[ot][r] + bm[o];
        }
}

// ---------------------------------------------------------------------------
extern "C" void kernel_launch(void* const* d_in, const int* in_sizes, int n_in,
                              void* d_out, int out_size, void* d_ws, size_t ws_size,
                              hipStream_t stream) {
    const float* query = (const float*)d_in[0];
    const float* key   = (const float*)d_in[1];
    const float* value = (const float*)d_in[2];
    const float* wq = (const float*)d_in[3];
    const float* bq = (const float*)d_in[4];
    const float* wk = (const float*)d_in[5];
    const float* bk = (const float*)d_in[6];
    const float* wv = (const float*)d_in[7];
    const float* bv = (const float*)d_in[8];
    const float* wm = (const float*)d_in[9];
    const float* bm = (const float*)d_in[10];

    float* out = (float*)d_out;
    char*  ws  = (char*)d_ws;

    const size_t TEN = (size_t)B_ * C_ * N_;            // 2,097,152

    // Layout (bytes):
    // [0, 16MB)        : Opart (2 x TEN f32)  -- Ximg (12MB) aliases here (dead before attn)
    // [16MB, +256KB)   : lpart
    // then Qb, Kimg, Vimg (4MB each), Whimg, Wlimg (512KB each)
    float*  Opart = (float*)ws;
    ushort* Ximg  = (ushort*)ws;
    float*  lpart = (float*)(ws + 2 * TEN * 4);
    ushort* Qb    = (ushort*)(ws + 2 * TEN * 4 + 262144);
    ushort* Kimg  = Qb + TEN;
    ushort* Vimg  = Kimg + TEN;
    ushort* Whimg = Vimg + TEN;
    ushort* Wlimg = Whimg + 4 * 65536;

    pack_w<<<dim3(4), dim3(256), 0, stream>>>(wq, wk, wv, wm, Whimg, Wlimg);
    pack_x<<<dim3(32, 8, 12), dim3(256), 0, stream>>>(query, key, value, Ximg);
    proj_mfma<<<dim3(64, 1, 12), dim3(256), 0, stream>>>(Ximg, Whimg, Wlimg,
                                                         bq, bk, bv, Qb, Kimg, Vimg);
    attn_v4<<<dim3(512), dim3(256), 0, stream>>>(Qb, Kimg, Vimg, Opart, lpart);
    conv_out<<<dim3(128, 4), dim3(256), 0, stream>>>(Opart, lpart, Whimg, Wlimg, bm, out);
}

// Round 5
// 80.669 us; speedup vs baseline: 4.7568x; 1.1691x over previous
//
#include <hip/hip_runtime.h>
#include <math.h>

#define B_ 4
#define C_ 256
#define N_ 2048
#define H_ 4
#define D_ 64

typedef __attribute__((ext_vector_type(8))) short bf16x8;
typedef __attribute__((ext_vector_type(4))) float f32x4;

#define QSCALE 0.18033688011112042f   // log2(e)/8

__device__ __forceinline__ float fexp2(float x) {
#if __has_builtin(__builtin_amdgcn_exp2f)
    return __builtin_amdgcn_exp2f(x);
#else
    float r;
    asm("v_exp_f32 %0, %1\n\ts_nop 1" : "=v"(r) : "v"(x));
    return r;
#endif
}

__device__ __forceinline__ ushort f2bf(float x) {
    uint u = __float_as_uint(x);
    uint r = (u + 0x7fffu + ((u >> 16) & 1u)) >> 16;
    return (ushort)r;
}
__device__ __forceinline__ float bf2f(ushort u) {
    return __uint_as_float((uint)u << 16);
}
__device__ __forceinline__ uint4 pack8(const ushort* v) {
    uint4 r;
    r.x = (uint)v[0] | ((uint)v[1] << 16);
    r.y = (uint)v[2] | ((uint)v[3] << 16);
    r.z = (uint)v[4] | ((uint)v[5] << 16);
    r.w = (uint)v[6] | ((uint)v[7] << 16);
    return r;
}
__device__ __forceinline__ void glds16(const void* g, void* l) {
    __builtin_amdgcn_global_load_lds(
        (const __attribute__((address_space(1))) unsigned int*)g,
        (__attribute__((address_space(3))) unsigned int*)l, 16, 0, 0);
}

// ---------------------------------------------------------------------------
// pack_w: W fp32 [o][c] -> hi/lo bf16 MFMA A-fragment images.
// Whimg[wsel][(ks*16+of)*64 + lane][8]: lane l holds W[of*16+(l&15)][32ks+(l>>4)*8+e]
// ---------------------------------------------------------------------------
__global__ __launch_bounds__(256) void pack_w(const float* __restrict__ w0,
                                              const float* __restrict__ w1,
                                              const float* __restrict__ w2,
                                              const float* __restrict__ w3,
                                              ushort* __restrict__ Whimg,
                                              ushort* __restrict__ Wlimg) {
    const int ws = blockIdx.x;
    const float* W = ws == 0 ? w0 : ws == 1 ? w1 : ws == 2 ? w2 : w3;
    ushort* Hh = Whimg + ws * 65536;
    ushort* Hl = Wlimg + ws * 65536;
    const int o  = threadIdx.x;
    const int of = o >> 4;
    const int li = o & 15;
#pragma unroll
    for (int ks = 0; ks < 8; ++ks) {
#pragma unroll
        for (int g = 0; g < 4; ++g) {
            float v[8];
            *(float4*)&v[0] = *(const float4*)&W[o * 256 + ks * 32 + g * 8];
            *(float4*)&v[4] = *(const float4*)&W[o * 256 + ks * 32 + g * 8 + 4];
            ushort hi[8], lo[8];
#pragma unroll
            for (int e = 0; e < 8; ++e) {
                hi[e] = f2bf(v[e]);
                lo[e] = f2bf(v[e] - bf2f(hi[e]));
            }
            const size_t dst = ((size_t)(ks * 16 + of) * 64 + (g * 16 + li)) * 8;
            *(uint4*)(Hh + dst) = pack8(hi);
            *(uint4*)(Hl + dst) = pack8(lo);
        }
    }
}

// ---------------------------------------------------------------------------
// proj_fused: reads fp32 X directly (no pack_x). Per ks-step stages a 32c x 32n
// fp32 tile via global_load_lds with pre-swizzled source (conflict-free
// transposed reads), converts to bf16 B-frags in-register, MFMA with W hi/lo.
// Epilogue packs to Qb / Kimg / Vimg (attention-ready layouts).
// ---------------------------------------------------------------------------
__global__ __launch_bounds__(256) void proj_fused(const float* __restrict__ Xq,
                                                  const float* __restrict__ Xk,
                                                  const float* __restrict__ Xv,
                                                  const ushort* __restrict__ Whimg,
                                                  const ushort* __restrict__ Wlimg,
                                                  const float* __restrict__ bq,
                                                  const float* __restrict__ bk,
                                                  const float* __restrict__ bv,
                                                  ushort* __restrict__ Qb,
                                                  ushort* __restrict__ Kimg,
                                                  ushort* __restrict__ Vimg) {
    __shared__ float Xs[2][1024];     // [c_loc 32][n_loc 32] (source-swizzled)
    __shared__ ushort Ls[32][264];    // epilogue bf16 tile [n][o]

    const int z   = blockIdx.z;       // sel*4+b
    const int sel = z >> 2, b = z & 3;
    const int nt  = blockIdx.x;       // n0 = nt*32
    const int n0  = nt * 32;
    const int tid  = threadIdx.x;
    const int wv   = tid >> 6;
    const int lane = tid & 63;
    const int li   = lane & 15;
    const int g    = lane >> 4;

    const float* X = (sel == 0 ? Xq : sel == 1 ? Xk : Xv) + (size_t)b * C_ * N_;
    const ushort* Wh  = Whimg + sel * 65536;
    const ushort* Wl  = Wlimg + sel * 65536;
    const float* bias = sel == 0 ? bq : sel == 1 ? bk : bv;

    // stage: LDS[c_loc][ns] = X[c][ns ^ (w<<3)]  (w = wave = (c_loc>>3)&3)
    const int c_row   = wv * 8 + (lane >> 3);
    const int src_col = (4 * (lane & 7)) ^ (wv << 3);

    glds16(X + (size_t)(0 * 32 + c_row) * N_ + n0 + src_col, &Xs[0][wv * 256]);
    __syncthreads();

    const f32x4 zv = {0.f, 0.f, 0.f, 0.f};
    f32x4 acc[4][2] = {{zv, zv}, {zv, zv}, {zv, zv}, {zv, zv}};

    int cur = 0;
    for (int ks = 0; ks < 8; ++ks) {
        if (ks < 7)
            glds16(X + (size_t)((ks + 1) * 32 + c_row) * N_ + n0 + src_col,
                   &Xs[cur ^ 1][wv * 256]);

        // B-frags: B[k=8g+e][col=n=16nf+li], read swizzle ns = n ^ (g<<3)
        bf16x8 xb[2];
#pragma unroll
        for (int nf = 0; nf < 2; ++nf) {
            ushort t[8];
            const int ns = (16 * nf + li) ^ (g << 3);
#pragma unroll
            for (int e = 0; e < 8; ++e)
                t[e] = f2bf(Xs[cur][(8 * g + e) * 32 + ns]);
            union { uint4 u; bf16x8 v; } cvt;
            cvt.u = pack8(t);
            xb[nf] = cvt.v;
        }

        const size_t abase = ((size_t)(ks * 16 + wv * 4) * 64 + lane) * 8;
#pragma unroll
        for (int ot = 0; ot < 4; ++ot) {
            const bf16x8 ah = *(const bf16x8*)(Wh + abase + (size_t)ot * 512);
            const bf16x8 al = *(const bf16x8*)(Wl + abase + (size_t)ot * 512);
#pragma unroll
            for (int nf = 0; nf < 2; ++nf) {
                f32x4 a = acc[ot][nf];
                a = __builtin_amdgcn_mfma_f32_16x16x32_bf16(al, xb[nf], a, 0, 0, 0);
                a = __builtin_amdgcn_mfma_f32_16x16x32_bf16(ah, xb[nf], a, 0, 0, 0);
                acc[ot][nf] = a;
            }
        }
        __syncthreads();
        cur ^= 1;
    }

    // ---- epilogue: bias (+scale for Q), stage bf16 tile Ls[n][o]
    const float scale = (sel == 0) ? QSCALE : 1.0f;
#pragma unroll
    for (int ot = 0; ot < 4; ++ot)
#pragma unroll
        for (int nf = 0; nf < 2; ++nf)
#pragma unroll
            for (int r = 0; r < 4; ++r) {
                const int o = wv * 64 + ot * 16 + g * 4 + r;
                Ls[nf * 16 + li][o] = f2bf((acc[ot][nf][r] + bias[o]) * scale);
            }
    __syncthreads();

    const int h  = tid >> 6;
    const int bh = b * 4 + h;
    if (sel == 0) {
#pragma unroll
        for (int r_ = 0; r_ < 4; ++r_) {
            const int gi = (tid & 63) + 64 * r_;
            const int n_l = gi >> 3, dr = gi & 7;
            ushort u[8];
#pragma unroll
            for (int e = 0; e < 8; ++e) u[e] = Ls[n_l][(dr * 8 + e) * 4 + h];
            *(uint4*)(Qb + (((size_t)bh * N_) + n0 + n_l) * 64 + dr * 8) = pack8(u);
        }
    } else if (sel == 1) {
#pragma unroll
        for (int r_ = 0; r_ < 4; ++r_) {
            const int gi = (tid & 63) + 64 * r_;
            const int n_l = gi >> 3, dr = gi & 7;
            ushort u[8];
#pragma unroll
            for (int e = 0; e < 8; ++e) u[e] = Ls[n_l][(dr * 8 + e) * 4 + h];
            const int jg    = n0 + n_l;
            const int j     = jg & 63;
            const int ktile = jg >> 6;
            *(uint4*)(Kimg + (((size_t)bh * 32 + ktile) << 12) + j * 64 +
                      ((dr * 8) ^ ((j & 7) << 3))) = pack8(u);
        }
    } else {
#pragma unroll
        for (int r_ = 0; r_ < 4; ++r_) {
            const int gi = (tid & 63) + 64 * r_;
            const int d = gi >> 2, jr = gi & 3;
            ushort u[8];
#pragma unroll
            for (int e = 0; e < 8; ++e) u[e] = Ls[jr * 8 + e][d * 4 + h];
            const int jbase = (nt & 1) * 32 + jr * 8;
            const int ktile = nt >> 1;
            *(uint4*)(Vimg + (((size_t)bh * 32 + ktile) << 12) + d * 64 +
                      (jbase ^ ((d & 7) << 3))) = pack8(u);
        }
    }
}

// ---------------------------------------------------------------------------
// attn_v5: split-K flash attention, max-free softmax, 64-query tiles.
// 1024 blocks = 2 splits x 16 bh x 32 qt -> 4 blocks/CU. LDS 24KB:
// single K/V buffer (reg-staged prefetch) + wave-private P. l accumulated
// via ones-MFMA. Writes unnormalized Opart[slot][q16][d64] + lpart.
// ---------------------------------------------------------------------------
__global__ __launch_bounds__(256) void attn_v5(const ushort* __restrict__ Qb,
                                               const ushort* __restrict__ Kimg,
                                               const ushort* __restrict__ Vimg,
                                               float* __restrict__ Opart,
                                               float* __restrict__ lpart) {
    __shared__ ushort SMEM[12288];   // K 8KB | V 8KB | P 8KB

    const int bid = blockIdx.x;
    const int xcd = bid & 7;
    const int r   = bid >> 3;                  // 0..127
    const int p   = xcd + 8 * (r >> 5);        // 0..31 : (bh,s) pair per XCD
    const int qt  = r & 31;
    const int bh  = p >> 1;
    const int s   = p & 1;

    const int tid  = threadIdx.x;
    const int wv   = tid >> 6;
    const int lane = tid & 63;
    const int li   = lane & 15;
    const int g    = lane >> 4;
    const int l7   = li & 7;
    const int i0w  = qt * 64 + wv * 16;

    // Q fragments (resident)
    bf16x8 qf[2];
#pragma unroll
    for (int ks = 0; ks < 2; ++ks)
        qf[ks] = *(const bf16x8*)(Qb + ((size_t)bh * N_ + i0w + li) * 64 + ks * 32 + g * 8);

    const ushort* Kg = Kimg + ((size_t)bh << 17);
    const ushort* Vg = Vimg + ((size_t)bh << 17);
    ushort* Pw = SMEM + 8192 + wv * 1024;      // 2KB/wave (16q x 64j bf16)

    const f32x4 z = {0.f, 0.f, 0.f, 0.f};
    f32x4 accO[4] = {z, z, z, z};
    f32x4 accL = z;
    const bf16x8 ones = {16256, 16256, 16256, 16256, 16256, 16256, 16256, 16256};

    const int kt0 = s * 16, kt1 = kt0 + 16;

    // prologue: stage tile kt0
    {
        const ushort* ksrc = Kg + ((size_t)kt0 << 12) + wv * 1024 + lane * 8;
        const ushort* vsrc = Vg + ((size_t)kt0 << 12) + wv * 1024 + lane * 8;
        glds16(ksrc,       SMEM + wv * 1024);
        glds16(ksrc + 512, SMEM + wv * 1024 + 512);
        glds16(vsrc,       SMEM + 4096 + wv * 1024);
        glds16(vsrc + 512, SMEM + 4096 + wv * 1024 + 512);
    }
    __syncthreads();

    for (int kt = kt0; kt < kt1; ++kt) {
        // reg-staged prefetch of next tile (issued early, written after barrier)
        uint4 nk0, nk1, nv0, nv1;
        const bool have = (kt + 1 < kt1);
        if (have) {
            const ushort* kn = Kg + ((size_t)(kt + 1) << 12) + wv * 1024 + lane * 8;
            const ushort* vn = Vg + ((size_t)(kt + 1) << 12) + wv * 1024 + lane * 8;
            nk0 = *(const uint4*)kn;
            nk1 = *(const uint4*)(kn + 512);
            nv0 = *(const uint4*)vn;
            nv1 = *(const uint4*)(vn + 512);
        }

        // ---- QK^T: lane holds S^T[j=16jt+4g+r][q=li]
        f32x4 sc[4];
#pragma unroll
        for (int jt = 0; jt < 4; ++jt) {
            const ushort* row = SMEM + (16 * jt + li) * 64;
            const bf16x8 kf0 = *(const bf16x8*)(row + 8 * (g ^ l7));
            const bf16x8 kf1 = *(const bf16x8*)(row + 8 * ((4 + g) ^ l7));
            f32x4 a = z;
            a = __builtin_amdgcn_mfma_f32_16x16x32_bf16(kf0, qf[0], a, 0, 0, 0);
            a = __builtin_amdgcn_mfma_f32_16x16x32_bf16(kf1, qf[1], a, 0, 0, 0);
            sc[jt] = a;
        }

        // ---- max-free softmax: p = exp2(s) (raw v_exp), write P^T to LDS
#pragma unroll
        for (int jt = 0; jt < 4; ++jt) {
            const float p0 = fexp2(sc[jt][0]);
            const float p1 = fexp2(sc[jt][1]);
            const float p2 = fexp2(sc[jt][2]);
            const float p3 = fexp2(sc[jt][3]);
            const uint a01 = (__float_as_uint(p1) & 0xffff0000u) | (__float_as_uint(p0) >> 16);
            const uint a23 = (__float_as_uint(p3) & 0xffff0000u) | (__float_as_uint(p2) >> 16);
            const uint byteoff = (uint)(li * 128) + (((uint)(jt * 32 + g * 8)) ^ ((uint)l7 << 4));
            *(uint2*)((char*)Pw + byteoff) = make_uint2(a01, a23);
        }

        // ---- P^T fragments back; l via ones-MFMA
        const bf16x8 pf0 = *(const bf16x8*)((char*)Pw + li * 128 + 16 * (g ^ l7));
        const bf16x8 pf1 = *(const bf16x8*)((char*)Pw + li * 128 + 16 * ((4 + g) ^ l7));
        accL = __builtin_amdgcn_mfma_f32_16x16x32_bf16(ones, pf0, accL, 0, 0, 0);
        accL = __builtin_amdgcn_mfma_f32_16x16x32_bf16(ones, pf1, accL, 0, 0, 0);

        // ---- PV
#pragma unroll
        for (int dt = 0; dt < 4; ++dt) {
            const ushort* row = SMEM + 4096 + (16 * dt + li) * 64;
            const bf16x8 vf0 = *(const bf16x8*)(row + 8 * (g ^ l7));
            const bf16x8 vf1 = *(const bf16x8*)(row + 8 * ((4 + g) ^ l7));
            f32x4 a = accO[dt];
            a = __builtin_amdgcn_mfma_f32_16x16x32_bf16(vf0, pf0, a, 0, 0, 0);
            a = __builtin_amdgcn_mfma_f32_16x16x32_bf16(vf1, pf1, a, 0, 0, 0);
            accO[dt] = a;
        }

        __syncthreads();                 // all waves done reading K/V
        if (have) {
            *(uint4*)(SMEM + wv * 1024 + lane * 8)              = nk0;
            *(uint4*)(SMEM + wv * 1024 + 512 + lane * 8)        = nk1;
            *(uint4*)(SMEM + 4096 + wv * 1024 + lane * 8)       = nv0;
            *(uint4*)(SMEM + 4096 + wv * 1024 + 512 + lane * 8) = nv1;
            __syncthreads();             // next tile visible
        }
    }

    // ---- epilogue: unnormalized O^T -> Opart[slot][q][d] (d-contiguous)
    const int slot = ((s * 16 + bh) * 32 + qt) * 4 + wv;
    float* Op = Opart + (size_t)slot * 1024;
#pragma unroll
    for (int dt = 0; dt < 4; ++dt)
        *(f32x4*)&Op[li * 64 + dt * 16 + g * 4] = accO[dt];
    if (g == 0) lpart[slot * 16 + li] = accL[0];
}

// ---------------------------------------------------------------------------
// conv_out: fused split-combine + output projection (bf16 MFMA, 3-product).
// Block: 256o x 16n. Combines 2 splits, divides by l, stages hi/lo bf16
// B-tile in LDS (granule-swizzled), 8 k-steps, writes fp32 out.
// ---------------------------------------------------------------------------
__global__ __launch_bounds__(256) void conv_out(const float* __restrict__ Opart,
                                                const float* __restrict__ lpart,
                                                const ushort* __restrict__ Whimg,
                                                const ushort* __restrict__ Wlimg,
                                                const float* __restrict__ bm,
                                                float* __restrict__ out) {
    __shared__ ushort Bh[512 * 8];
    __shared__ ushort Bl[512 * 8];
    __shared__ float Linv[4][16];

    const int bx  = blockIdx.x;        // 0..127
    const int b   = blockIdx.y;        // 0..3
    const int n0  = bx * 16;
    const int qt  = bx >> 2;           // 64q-tile
    const int wq  = bx & 3;            // wave slot within tile
    const int tid = threadIdx.x;

    if (tid < 64) {
        const int h = tid >> 4, q = tid & 15;
        const int sl0 = (((0 * 16 + b * 4 + h) * 32 + qt) * 4 + wq);
        const int sl1 = (((1 * 16 + b * 4 + h) * 32 + qt) * 4 + wq);
        Linv[h][q] = 1.0f / (lpart[sl0 * 16 + q] + lpart[sl1 * 16 + q]);
    }
    __syncthreads();

#pragma unroll
    for (int it = 0; it < 4; ++it) {
        const int id = tid + 256 * it;        // 0..1023 = (h,q,d4)
        const int h  = id >> 8;
        const int q  = (id >> 4) & 15;
        const int d4 = id & 15;
        const size_t sl0 = (size_t)(((0 * 16 + b * 4 + h) * 32 + qt) * 4 + wq);
        const size_t sl1 = (size_t)(((1 * 16 + b * 4 + h) * 32 + qt) * 4 + wq);
        const f32x4 v0 = *(const f32x4*)&Opart[sl0 * 1024 + q * 64 + d4 * 4];
        const f32x4 v1 = *(const f32x4*)&Opart[sl1 * 1024 + q * 64 + d4 * 4];
        const float li_ = Linv[h][q];
#pragma unroll
        for (int e = 0; e < 4; ++e) {
            const int d = d4 * 4 + e;
            const float vv = (v0[e] + v1[e]) * li_;
            const ushort hi = f2bf(vv);
            const ushort lo = f2bf(vv - bf2f(hi));
            const int cg = d >> 1;
            const int eb = (d & 1) * 4 + h;
            const int Gp = (q * 32 + cg) ^ (q & 7);
            Bh[Gp * 8 + eb] = hi;
            Bl[Gp * 8 + eb] = lo;
        }
    }
    __syncthreads();

    const int wv = tid >> 6, lane = tid & 63, li = lane & 15, g = lane >> 4;
    const ushort* Wh = Whimg + 3 * 65536;
    const ushort* Wl = Wlimg + 3 * 65536;
    const f32x4 zv = {0.f, 0.f, 0.f, 0.f};
    f32x4 acc[4] = {zv, zv, zv, zv};

    for (int ks = 0; ks < 8; ++ks) {
        const int Gp = (li * 32 + ks * 4 + g) ^ (li & 7);
        const bf16x8 bh_ = *(const bf16x8*)(Bh + Gp * 8);
        const bf16x8 bl_ = *(const bf16x8*)(Bl + Gp * 8);
        const size_t abase = ((size_t)(ks * 16 + wv * 4) * 64 + lane) * 8;
#pragma unroll
        for (int ot = 0; ot < 4; ++ot) {
            const bf16x8 ah = *(const bf16x8*)(Wh + abase + (size_t)ot * 512);
            const bf16x8 al = *(const bf16x8*)(Wl + abase + (size_t)ot * 512);
            f32x4 a = acc[ot];
            a = __builtin_amdgcn_mfma_f32_16x16x32_bf16(ah, bl_, a, 0, 0, 0);
            a = __builtin_amdgcn_mfma_f32_16x16x32_bf16(al, bh_, a, 0, 0, 0);
            a = __builtin_amdgcn_mfma_f32_16x16x32_bf16(ah, bh_, a, 0, 0, 0);
            acc[ot] = a;
        }
    }

#pragma unroll
    for (int ot = 0; ot < 4; ++ot)
#pragma unroll
        for (int r = 0; r < 4; ++r) {
            const int o = wv * 64 + ot * 16 + g * 4 + r;
            out[((size_t)(b * 256 + o)) * N_ + n0 + li] = acc[ot][r] + bm[o];
        }
}

// ---------------------------------------------------------------------------
extern "C" void kernel_launch(void* const* d_in, const int* in_sizes, int n_in,
                              void* d_out, int out_size, void* d_ws, size_t ws_size,
                              hipStream_t stream) {
    const float* query = (const float*)d_in[0];
    const float* key   = (const float*)d_in[1];
    const float* value = (const float*)d_in[2];
    const float* wq = (const float*)d_in[3];
    const float* bq = (const float*)d_in[4];
    const float* wk = (const float*)d_in[5];
    const float* bk = (const float*)d_in[6];
    const float* wv = (const float*)d_in[7];
    const float* bv = (const float*)d_in[8];
    const float* wm = (const float*)d_in[9];
    const float* bm = (const float*)d_in[10];

    float* out = (float*)d_out;
    char*  ws  = (char*)d_ws;

    const size_t TEN = (size_t)B_ * C_ * N_;            // 2,097,152

    // Layout: Opart 16MB | lpart 256KB | Qb 4MB | Kimg 4MB | Vimg 4MB | W imgs 1MB
    float*  Opart = (float*)ws;
    float*  lpart = (float*)(ws + (size_t)4096 * 1024 * 4);
    ushort* Qb    = (ushort*)(ws + (size_t)4096 * 1024 * 4 + 262144);
    ushort* Kimg  = Qb + TEN;
    ushort* Vimg  = Kimg + TEN;
    ushort* Whimg = Vimg + TEN;
    ushort* Wlimg = Whimg + 4 * 65536;

    pack_w<<<dim3(4), dim3(256), 0, stream>>>(wq, wk, wv, wm, Whimg, Wlimg);
    proj_fused<<<dim3(64, 1, 12), dim3(256), 0, stream>>>(query, key, value,
                                                          Whimg, Wlimg, bq, bk, bv,
                                                          Qb, Kimg, Vimg);
    attn_v5<<<dim3(1024), dim3(256), 0, stream>>>(Qb, Kimg, Vimg, Opart, lpart);
    conv_out<<<dim3(128, 4), dim3(256), 0, stream>>>(Opart, lpart, Whimg, Wlimg, bm, out);
}

// Round 6
// 72.936 us; speedup vs baseline: 5.2612x; 1.1060x over previous
//
#include <hip/hip_runtime.h>
#include <math.h>

#define B_ 4
#define C_ 256
#define N_ 2048
#define H_ 4
#define D_ 64

typedef __attribute__((ext_vector_type(8))) short bf16x8;
typedef __attribute__((ext_vector_type(4))) float f32x4;

#define QSCALE 0.18033688011112042f   // log2(e)/8

__device__ __forceinline__ float fexp2(float x) {
#if __has_builtin(__builtin_amdgcn_exp2f)
    return __builtin_amdgcn_exp2f(x);
#else
    float r;
    asm("v_exp_f32 %0, %1\n\ts_nop 1" : "=v"(r) : "v"(x));
    return r;
#endif
}

__device__ __forceinline__ ushort f2bf(float x) {
    uint u = __float_as_uint(x);
    uint r = (u + 0x7fffu + ((u >> 16) & 1u)) >> 16;
    return (ushort)r;
}
__device__ __forceinline__ float bf2f(ushort u) {
    return __uint_as_float((uint)u << 16);
}
__device__ __forceinline__ uint4 pack8(const ushort* v) {
    uint4 r;
    r.x = (uint)v[0] | ((uint)v[1] << 16);
    r.y = (uint)v[2] | ((uint)v[3] << 16);
    r.z = (uint)v[4] | ((uint)v[5] << 16);
    r.w = (uint)v[6] | ((uint)v[7] << 16);
    return r;
}
__device__ __forceinline__ void glds16(const void* g, void* l) {
    __builtin_amdgcn_global_load_lds(
        (const __attribute__((address_space(1))) unsigned int*)g,
        (__attribute__((address_space(3))) unsigned int*)l, 16, 0, 0);
}

// ---------------------------------------------------------------------------
// pack_w (parallelized): W fp32 [o][c] -> hi/lo bf16 MFMA A-fragment images.
// Whimg[wsel][(ks*16+of)*64 + lane][8]: lane l holds W[of*16+(l&15)][32ks+(l>>4)*8+e]
// Grid (4 wsel, 8 ks) x 256 threads (thread = o); 8 float4 loads/thread.
// ---------------------------------------------------------------------------
__global__ __launch_bounds__(256) void pack_w(const float* __restrict__ w0,
                                              const float* __restrict__ w1,
                                              const float* __restrict__ w2,
                                              const float* __restrict__ w3,
                                              ushort* __restrict__ Whimg,
                                              ushort* __restrict__ Wlimg) {
    const int ws = blockIdx.x;
    const int ks = blockIdx.y;
    const float* W = ws == 0 ? w0 : ws == 1 ? w1 : ws == 2 ? w2 : w3;
    ushort* Hh = Whimg + ws * 65536;
    ushort* Hl = Wlimg + ws * 65536;
    const int o  = threadIdx.x;
    const int of = o >> 4;
    const int li = o & 15;

    float v[32];
#pragma unroll
    for (int q = 0; q < 8; ++q)
        *(float4*)&v[q * 4] = *(const float4*)&W[o * 256 + ks * 32 + q * 4];

#pragma unroll
    for (int g = 0; g < 4; ++g) {
        ushort hi[8], lo[8];
#pragma unroll
        for (int e = 0; e < 8; ++e) {
            const float x = v[g * 8 + e];
            hi[e] = f2bf(x);
            lo[e] = f2bf(x - bf2f(hi[e]));
        }
        const size_t dst = ((size_t)(ks * 16 + of) * 64 + (g * 16 + li)) * 8;
        *(uint4*)(Hh + dst) = pack8(hi);
        *(uint4*)(Hl + dst) = pack8(lo);
    }
}

// ---------------------------------------------------------------------------
// proj_fused: reads fp32 X directly. Per ks-step stages a 32c x 32n fp32 tile
// via global_load_lds with pre-swizzled source (conflict-free transposed
// reads), converts to bf16 B-frags in-register, MFMA with W hi/lo.
// Epilogue packs to Qb / Kimg / Vimg (attention-ready layouts).
// ---------------------------------------------------------------------------
__global__ __launch_bounds__(256) void proj_fused(const float* __restrict__ Xq,
                                                  const float* __restrict__ Xk,
                                                  const float* __restrict__ Xv,
                                                  const ushort* __restrict__ Whimg,
                                                  const ushort* __restrict__ Wlimg,
                                                  const float* __restrict__ bq,
                                                  const float* __restrict__ bk,
                                                  const float* __restrict__ bv,
                                                  ushort* __restrict__ Qb,
                                                  ushort* __restrict__ Kimg,
                                                  ushort* __restrict__ Vimg) {
    __shared__ float Xs[2][1024];     // [c_loc 32][n_loc 32] (source-swizzled)
    __shared__ ushort Ls[32][264];    // epilogue bf16 tile [n][o]

    const int z   = blockIdx.z;       // sel*4+b
    const int sel = z >> 2, b = z & 3;
    const int nt  = blockIdx.x;       // n0 = nt*32
    const int n0  = nt * 32;
    const int tid  = threadIdx.x;
    const int wv   = tid >> 6;
    const int lane = tid & 63;
    const int li   = lane & 15;
    const int g    = lane >> 4;

    const float* X = (sel == 0 ? Xq : sel == 1 ? Xk : Xv) + (size_t)b * C_ * N_;
    const ushort* Wh  = Whimg + sel * 65536;
    const ushort* Wl  = Wlimg + sel * 65536;
    const float* bias = sel == 0 ? bq : sel == 1 ? bk : bv;

    const int c_row   = wv * 8 + (lane >> 3);
    const int src_col = (4 * (lane & 7)) ^ (wv << 3);

    glds16(X + (size_t)(0 * 32 + c_row) * N_ + n0 + src_col, &Xs[0][wv * 256]);
    __syncthreads();

    const f32x4 zv = {0.f, 0.f, 0.f, 0.f};
    f32x4 acc[4][2] = {{zv, zv}, {zv, zv}, {zv, zv}, {zv, zv}};

    int cur = 0;
    for (int ks = 0; ks < 8; ++ks) {
        if (ks < 7)
            glds16(X + (size_t)((ks + 1) * 32 + c_row) * N_ + n0 + src_col,
                   &Xs[cur ^ 1][wv * 256]);

        bf16x8 xb[2];
#pragma unroll
        for (int nf = 0; nf < 2; ++nf) {
            ushort t[8];
            const int ns = (16 * nf + li) ^ (g << 3);
#pragma unroll
            for (int e = 0; e < 8; ++e)
                t[e] = f2bf(Xs[cur][(8 * g + e) * 32 + ns]);
            union { uint4 u; bf16x8 v; } cvt;
            cvt.u = pack8(t);
            xb[nf] = cvt.v;
        }

        const size_t abase = ((size_t)(ks * 16 + wv * 4) * 64 + lane) * 8;
#pragma unroll
        for (int ot = 0; ot < 4; ++ot) {
            const bf16x8 ah = *(const bf16x8*)(Wh + abase + (size_t)ot * 512);
            const bf16x8 al = *(const bf16x8*)(Wl + abase + (size_t)ot * 512);
#pragma unroll
            for (int nf = 0; nf < 2; ++nf) {
                f32x4 a = acc[ot][nf];
                a = __builtin_amdgcn_mfma_f32_16x16x32_bf16(al, xb[nf], a, 0, 0, 0);
                a = __builtin_amdgcn_mfma_f32_16x16x32_bf16(ah, xb[nf], a, 0, 0, 0);
                acc[ot][nf] = a;
            }
        }
        __syncthreads();
        cur ^= 1;
    }

    const float scale = (sel == 0) ? QSCALE : 1.0f;
#pragma unroll
    for (int ot = 0; ot < 4; ++ot)
#pragma unroll
        for (int nf = 0; nf < 2; ++nf)
#pragma unroll
            for (int r = 0; r < 4; ++r) {
                const int o = wv * 64 + ot * 16 + g * 4 + r;
                Ls[nf * 16 + li][o] = f2bf((acc[ot][nf][r] + bias[o]) * scale);
            }
    __syncthreads();

    const int h  = tid >> 6;
    const int bh = b * 4 + h;
    if (sel == 0) {
#pragma unroll
        for (int r_ = 0; r_ < 4; ++r_) {
            const int gi = (tid & 63) + 64 * r_;
            const int n_l = gi >> 3, dr = gi & 7;
            ushort u[8];
#pragma unroll
            for (int e = 0; e < 8; ++e) u[e] = Ls[n_l][(dr * 8 + e) * 4 + h];
            *(uint4*)(Qb + (((size_t)bh * N_) + n0 + n_l) * 64 + dr * 8) = pack8(u);
        }
    } else if (sel == 1) {
#pragma unroll
        for (int r_ = 0; r_ < 4; ++r_) {
            const int gi = (tid & 63) + 64 * r_;
            const int n_l = gi >> 3, dr = gi & 7;
            ushort u[8];
#pragma unroll
            for (int e = 0; e < 8; ++e) u[e] = Ls[n_l][(dr * 8 + e) * 4 + h];
            const int jg    = n0 + n_l;
            const int j     = jg & 63;
            const int ktile = jg >> 6;
            *(uint4*)(Kimg + (((size_t)bh * 32 + ktile) << 12) + j * 64 +
                      ((dr * 8) ^ ((j & 7) << 3))) = pack8(u);
        }
    } else {
#pragma unroll
        for (int r_ = 0; r_ < 4; ++r_) {
            const int gi = (tid & 63) + 64 * r_;
            const int d = gi >> 2, jr = gi & 3;
            ushort u[8];
#pragma unroll
            for (int e = 0; e < 8; ++e) u[e] = Ls[jr * 8 + e][d * 4 + h];
            const int jbase = (nt & 1) * 32 + jr * 8;
            const int ktile = nt >> 1;
            *(uint4*)(Vimg + (((size_t)bh * 32 + ktile) << 12) + d * 64 +
                      (jbase ^ ((d & 7) << 3))) = pack8(u);
        }
    }
}

// ---------------------------------------------------------------------------
// attn_v5: split-K flash attention, max-free softmax, 64-query tiles.
// 1024 blocks = 2 splits x 16 bh x 32 qt -> 4 blocks/CU. LDS 24KB:
// single K/V buffer (reg-staged prefetch) + wave-private P. l accumulated
// via ones-MFMA. Writes unnormalized Opart[slot][q16][d64] + lpart.
// ---------------------------------------------------------------------------
__global__ __launch_bounds__(256) void attn_v5(const ushort* __restrict__ Qb,
                                               const ushort* __restrict__ Kimg,
                                               const ushort* __restrict__ Vimg,
                                               float* __restrict__ Opart,
                                               float* __restrict__ lpart) {
    __shared__ ushort SMEM[12288];   // K 8KB | V 8KB | P 8KB

    const int bid = blockIdx.x;
    const int xcd = bid & 7;
    const int r   = bid >> 3;                  // 0..127
    const int p   = xcd + 8 * (r >> 5);        // 0..31 : (bh,s) pair per XCD
    const int qt  = r & 31;
    const int bh  = p >> 1;
    const int s   = p & 1;

    const int tid  = threadIdx.x;
    const int wv   = tid >> 6;
    const int lane = tid & 63;
    const int li   = lane & 15;
    const int g    = lane >> 4;
    const int l7   = li & 7;
    const int i0w  = qt * 64 + wv * 16;

    bf16x8 qf[2];
#pragma unroll
    for (int ks = 0; ks < 2; ++ks)
        qf[ks] = *(const bf16x8*)(Qb + ((size_t)bh * N_ + i0w + li) * 64 + ks * 32 + g * 8);

    const ushort* Kg = Kimg + ((size_t)bh << 17);
    const ushort* Vg = Vimg + ((size_t)bh << 17);
    ushort* Pw = SMEM + 8192 + wv * 1024;      // 2KB/wave (16q x 64j bf16)

    const f32x4 z = {0.f, 0.f, 0.f, 0.f};
    f32x4 accO[4] = {z, z, z, z};
    f32x4 accL = z;
    const bf16x8 ones = {16256, 16256, 16256, 16256, 16256, 16256, 16256, 16256};

    const int kt0 = s * 16, kt1 = kt0 + 16;

    {
        const ushort* ksrc = Kg + ((size_t)kt0 << 12) + wv * 1024 + lane * 8;
        const ushort* vsrc = Vg + ((size_t)kt0 << 12) + wv * 1024 + lane * 8;
        glds16(ksrc,       SMEM + wv * 1024);
        glds16(ksrc + 512, SMEM + wv * 1024 + 512);
        glds16(vsrc,       SMEM + 4096 + wv * 1024);
        glds16(vsrc + 512, SMEM + 4096 + wv * 1024 + 512);
    }
    __syncthreads();

    for (int kt = kt0; kt < kt1; ++kt) {
        uint4 nk0, nk1, nv0, nv1;
        const bool have = (kt + 1 < kt1);
        if (have) {
            const ushort* kn = Kg + ((size_t)(kt + 1) << 12) + wv * 1024 + lane * 8;
            const ushort* vn = Vg + ((size_t)(kt + 1) << 12) + wv * 1024 + lane * 8;
            nk0 = *(const uint4*)kn;
            nk1 = *(const uint4*)(kn + 512);
            nv0 = *(const uint4*)vn;
            nv1 = *(const uint4*)(vn + 512);
        }

        f32x4 sc[4];
#pragma unroll
        for (int jt = 0; jt < 4; ++jt) {
            const ushort* row = SMEM + (16 * jt + li) * 64;
            const bf16x8 kf0 = *(const bf16x8*)(row + 8 * (g ^ l7));
            const bf16x8 kf1 = *(const bf16x8*)(row + 8 * ((4 + g) ^ l7));
            f32x4 a = z;
            a = __builtin_amdgcn_mfma_f32_16x16x32_bf16(kf0, qf[0], a, 0, 0, 0);
            a = __builtin_amdgcn_mfma_f32_16x16x32_bf16(kf1, qf[1], a, 0, 0, 0);
            sc[jt] = a;
        }

#pragma unroll
        for (int jt = 0; jt < 4; ++jt) {
            const float p0 = fexp2(sc[jt][0]);
            const float p1 = fexp2(sc[jt][1]);
            const float p2 = fexp2(sc[jt][2]);
            const float p3 = fexp2(sc[jt][3]);
            const uint a01 = (__float_as_uint(p1) & 0xffff0000u) | (__float_as_uint(p0) >> 16);
            const uint a23 = (__float_as_uint(p3) & 0xffff0000u) | (__float_as_uint(p2) >> 16);
            const uint byteoff = (uint)(li * 128) + (((uint)(jt * 32 + g * 8)) ^ ((uint)l7 << 4));
            *(uint2*)((char*)Pw + byteoff) = make_uint2(a01, a23);
        }

        const bf16x8 pf0 = *(const bf16x8*)((char*)Pw + li * 128 + 16 * (g ^ l7));
        const bf16x8 pf1 = *(const bf16x8*)((char*)Pw + li * 128 + 16 * ((4 + g) ^ l7));
        accL = __builtin_amdgcn_mfma_f32_16x16x32_bf16(ones, pf0, accL, 0, 0, 0);
        accL = __builtin_amdgcn_mfma_f32_16x16x32_bf16(ones, pf1, accL, 0, 0, 0);

#pragma unroll
        for (int dt = 0; dt < 4; ++dt) {
            const ushort* row = SMEM + 4096 + (16 * dt + li) * 64;
            const bf16x8 vf0 = *(const bf16x8*)(row + 8 * (g ^ l7));
            const bf16x8 vf1 = *(const bf16x8*)(row + 8 * ((4 + g) ^ l7));
            f32x4 a = accO[dt];
            a = __builtin_amdgcn_mfma_f32_16x16x32_bf16(vf0, pf0, a, 0, 0, 0);
            a = __builtin_amdgcn_mfma_f32_16x16x32_bf16(vf1, pf1, a, 0, 0, 0);
            accO[dt] = a;
        }

        __syncthreads();
        if (have) {
            *(uint4*)(SMEM + wv * 1024 + lane * 8)              = nk0;
            *(uint4*)(SMEM + wv * 1024 + 512 + lane * 8)        = nk1;
            *(uint4*)(SMEM + 4096 + wv * 1024 + lane * 8)       = nv0;
            *(uint4*)(SMEM + 4096 + wv * 1024 + 512 + lane * 8) = nv1;
            __syncthreads();
        }
    }

    const int slot = ((s * 16 + bh) * 32 + qt) * 4 + wv;
    float* Op = Opart + (size_t)slot * 1024;
#pragma unroll
    for (int dt = 0; dt < 4; ++dt)
        *(f32x4*)&Op[li * 64 + dt * 16 + g * 4] = accO[dt];
    if (g == 0) lpart[slot * 16 + li] = accL[0];
}

// ---------------------------------------------------------------------------
// conv_out: fused split-combine + output projection (bf16 MFMA, 3-product).
// ---------------------------------------------------------------------------
__global__ __launch_bounds__(256) void conv_out(const float* __restrict__ Opart,
                                                const float* __restrict__ lpart,
                                                const ushort* __restrict__ Whimg,
                                                const ushort* __restrict__ Wlimg,
                                                const float* __restrict__ bm,
                                                float* __restrict__ out) {
    __shared__ ushort Bh[512 * 8];
    __shared__ ushort Bl[512 * 8];
    __shared__ float Linv[4][16];

    const int bx  = blockIdx.x;        // 0..127
    const int b   = blockIdx.y;        // 0..3
    const int n0  = bx * 16;
    const int qt  = bx >> 2;           // 64q-tile
    const int wq  = bx & 3;            // wave slot within tile
    const int tid = threadIdx.x;

    if (tid < 64) {
        const int h = tid >> 4, q = tid & 15;
        const int sl0 = (((0 * 16 + b * 4 + h) * 32 + qt) * 4 + wq);
        const int sl1 = (((1 * 16 + b * 4 + h) * 32 + qt) * 4 + wq);
        Linv[h][q] = 1.0f / (lpart[sl0 * 16 + q] + lpart[sl1 * 16 + q]);
    }
    __syncthreads();

#pragma unroll
    for (int it = 0; it < 4; ++it) {
        const int id = tid + 256 * it;        // 0..1023 = (h,q,d4)
        const int h  = id >> 8;
        const int q  = (id >> 4) & 15;
        const int d4 = id & 15;
        const size_t sl0 = (size_t)(((0 * 16 + b * 4 + h) * 32 + qt) * 4 + wq);
        const size_t sl1 = (size_t)(((1 * 16 + b * 4 + h) * 32 + qt) * 4 + wq);
        const f32x4 v0 = *(const f32x4*)&Opart[sl0 * 1024 + q * 64 + d4 * 4];
        const f32x4 v1 = *(const f32x4*)&Opart[sl1 * 1024 + q * 64 + d4 * 4];
        const float li_ = Linv[h][q];
#pragma unroll
        for (int e = 0; e < 4; ++e) {
            const int d = d4 * 4 + e;
            const float vv = (v0[e] + v1[e]) * li_;
            const ushort hi = f2bf(vv);
            const ushort lo = f2bf(vv - bf2f(hi));
            const int cg = d >> 1;
            const int eb = (d & 1) * 4 + h;
            const int Gp = (q * 32 + cg) ^ (q & 7);
            Bh[Gp * 8 + eb] = hi;
            Bl[Gp * 8 + eb] = lo;
        }
    }
    __syncthreads();

    const int wv = tid >> 6, lane = tid & 63, li = lane & 15, g = lane >> 4;
    const ushort* Wh = Whimg + 3 * 65536;
    const ushort* Wl = Wlimg + 3 * 65536;
    const f32x4 zv = {0.f, 0.f, 0.f, 0.f};
    f32x4 acc[4] = {zv, zv, zv, zv};

    for (int ks = 0; ks < 8; ++ks) {
        const int Gp = (li * 32 + ks * 4 + g) ^ (li & 7);
        const bf16x8 bh_ = *(const bf16x8*)(Bh + Gp * 8);
        const bf16x8 bl_ = *(const bf16x8*)(Bl + Gp * 8);
        const size_t abase = ((size_t)(ks * 16 + wv * 4) * 64 + lane) * 8;
#pragma unroll
        for (int ot = 0; ot < 4; ++ot) {
            const bf16x8 ah = *(const bf16x8*)(Wh + abase + (size_t)ot * 512);
            const bf16x8 al = *(const bf16x8*)(Wl + abase + (size_t)ot * 512);
            f32x4 a = acc[ot];
            a = __builtin_amdgcn_mfma_f32_16x16x32_bf16(ah, bl_, a, 0, 0, 0);
            a = __builtin_amdgcn_mfma_f32_16x16x32_bf16(al, bh_, a, 0, 0, 0);
            a = __builtin_amdgcn_mfma_f32_16x16x32_bf16(ah, bh_, a, 0, 0, 0);
            acc[ot] = a;
        }
    }

#pragma unroll
    for (int ot = 0; ot < 4; ++ot)
#pragma unroll
        for (int r = 0; r < 4; ++r) {
            const int o = wv * 64 + ot * 16 + g * 4 + r;
            out[((size_t)(b * 256 + o)) * N_ + n0 + li] = acc[ot][r] + bm[o];
        }
}

// ---------------------------------------------------------------------------
extern "C" void kernel_launch(void* const* d_in, const int* in_sizes, int n_in,
                              void* d_out, int out_size, void* d_ws, size_t ws_size,
                              hipStream_t stream) {
    const float* query = (const float*)d_in[0];
    const float* key   = (const float*)d_in[1];
    const float* value = (const float*)d_in[2];
    const float* wq = (const float*)d_in[3];
    const float* bq = (const float*)d_in[4];
    const float* wk = (const float*)d_in[5];
    const float* bk = (const float*)d_in[6];
    const float* wv = (const float*)d_in[7];
    const float* bv = (const float*)d_in[8];
    const float* wm = (const float*)d_in[9];
    const float* bm = (const float*)d_in[10];

    float* out = (float*)d_out;
    char*  ws  = (char*)d_ws;

    const size_t TEN = (size_t)B_ * C_ * N_;            // 2,097,152

    float*  Opart = (float*)ws;
    float*  lpart = (float*)(ws + (size_t)4096 * 1024 * 4);
    ushort* Qb    = (ushort*)(ws + (size_t)4096 * 1024 * 4 + 262144);
    ushort* Kimg  = Qb + TEN;
    ushort* Vimg  = Kimg + TEN;
    ushort* Whimg = Vimg + TEN;
    ushort* Wlimg = Whimg + 4 * 65536;

    pack_w<<<dim3(4, 8), dim3(256), 0, stream>>>(wq, wk, wv, wm, Whimg, Wlimg);
    proj_fused<<<dim3(64, 1, 12), dim3(256), 0, stream>>>(query, key, value,
                                                          Whimg, Wlimg, bq, bk, bv,
                                                          Qb, Kimg, Vimg);
    attn_v5<<<dim3(1024), dim3(256), 0, stream>>>(Qb, Kimg, Vimg, Opart, lpart);
    conv_out<<<dim3(128, 4), dim3(256), 0, stream>>>(Opart, lpart, Whimg, Wlimg, bm, out);
}

// Round 7
// 72.804 us; speedup vs baseline: 5.2707x; 1.0018x over previous
//
#include <hip/hip_runtime.h>
#include <math.h>

#define B_ 4
#define C_ 256
#define N_ 2048
#define H_ 4
#define D_ 64

typedef __attribute__((ext_vector_type(8))) short bf16x8;
typedef __attribute__((ext_vector_type(4))) float f32x4;

#define QSCALE 0.18033688011112042f   // log2(e)/8

__device__ __forceinline__ float fexp2(float x) {
#if __has_builtin(__builtin_amdgcn_exp2f)
    return __builtin_amdgcn_exp2f(x);
#else
    float r;
    asm("v_exp_f32 %0, %1\n\ts_nop 1" : "=v"(r) : "v"(x));
    return r;
#endif
}

__device__ __forceinline__ ushort f2bf(float x) {
    uint u = __float_as_uint(x);
    uint r = (u + 0x7fffu + ((u >> 16) & 1u)) >> 16;
    return (ushort)r;
}
__device__ __forceinline__ float bf2f(ushort u) {
    return __uint_as_float((uint)u << 16);
}
__device__ __forceinline__ uint4 pack8(const ushort* v) {
    uint4 r;
    r.x = (uint)v[0] | ((uint)v[1] << 16);
    r.y = (uint)v[2] | ((uint)v[3] << 16);
    r.z = (uint)v[4] | ((uint)v[5] << 16);
    r.w = (uint)v[6] | ((uint)v[7] << 16);
    return r;
}
__device__ __forceinline__ void glds16(const void* g, void* l) {
    __builtin_amdgcn_global_load_lds(
        (const __attribute__((address_space(1))) unsigned int*)g,
        (__attribute__((address_space(3))) unsigned int*)l, 16, 0, 0);
}

// ---------------------------------------------------------------------------
// pack_w: W fp32 [o][c] -> hi/lo bf16 MFMA A-fragment images.
// Whimg[wsel][(ks*16+of)*64 + lane][8]: lane l holds W[of*16+(l&15)][32ks+(l>>4)*8+e]
// ---------------------------------------------------------------------------
__global__ __launch_bounds__(256) void pack_w(const float* __restrict__ w0,
                                              const float* __restrict__ w1,
                                              const float* __restrict__ w2,
                                              const float* __restrict__ w3,
                                              ushort* __restrict__ Whimg,
                                              ushort* __restrict__ Wlimg) {
    const int ws = blockIdx.x;
    const int ks = blockIdx.y;
    const float* W = ws == 0 ? w0 : ws == 1 ? w1 : ws == 2 ? w2 : w3;
    ushort* Hh = Whimg + ws * 65536;
    ushort* Hl = Wlimg + ws * 65536;
    const int o  = threadIdx.x;
    const int of = o >> 4;
    const int li = o & 15;

    float v[32];
#pragma unroll
    for (int q = 0; q < 8; ++q)
        *(float4*)&v[q * 4] = *(const float4*)&W[o * 256 + ks * 32 + q * 4];

#pragma unroll
    for (int g = 0; g < 4; ++g) {
        ushort hi[8], lo[8];
#pragma unroll
        for (int e = 0; e < 8; ++e) {
            const float x = v[g * 8 + e];
            hi[e] = f2bf(x);
            lo[e] = f2bf(x - bf2f(hi[e]));
        }
        const size_t dst = ((size_t)(ks * 16 + of) * 64 + (g * 16 + li)) * 8;
        *(uint4*)(Hh + dst) = pack8(hi);
        *(uint4*)(Hl + dst) = pack8(lo);
    }
}

// ---------------------------------------------------------------------------
// proj_fused v2: fp32 X read directly; 3-stage pipeline per ks-step
// (glds ks+2 | convert ks+1 fp32->bf16 (deduped, once per block) | MFMA ks),
// ONE barrier per step. bf16 tile Xb[n][c] with 8B-chunk XOR swizzle
// (j' = j ^ (n&6)) -> conflict-free b64 writes and b128 frag reads.
// Epilogue packs to Qb / Kimg / Vimg (attention-ready layouts).
// ---------------------------------------------------------------------------
__global__ __launch_bounds__(256) void proj_fused(const float* __restrict__ Xq,
                                                  const float* __restrict__ Xk,
                                                  const float* __restrict__ Xv,
                                                  const ushort* __restrict__ Whimg,
                                                  const ushort* __restrict__ Wlimg,
                                                  const float* __restrict__ bq,
                                                  const float* __restrict__ bk,
                                                  const float* __restrict__ bv,
                                                  ushort* __restrict__ Qb,
                                                  ushort* __restrict__ Kimg,
                                                  ushort* __restrict__ Vimg) {
    __shared__ float  Xf[2][1024];    // fp32 staging [c32][n32], linear, dbuf
    __shared__ ushort Xb[2][1024];    // bf16 frag tile [n32][c32], chunk-XOR, dbuf
    __shared__ ushort Ls[32][264];    // epilogue bf16 tile [n][o]

    const int z   = blockIdx.z;       // sel*4+b
    const int sel = z >> 2, b = z & 3;
    const int nt  = blockIdx.x;       // n0 = nt*32
    const int n0  = nt * 32;
    const int tid  = threadIdx.x;
    const int wv   = tid >> 6;
    const int lane = tid & 63;
    const int li   = lane & 15;
    const int g    = lane >> 4;

    const float* X = (sel == 0 ? Xq : sel == 1 ? Xk : Xv) + (size_t)b * C_ * N_;
    const ushort* Wh  = Whimg + sel * 65536;
    const ushort* Wl  = Wlimg + sel * 65536;
    const float* bias = sel == 0 ? bq : sel == 1 ? bk : bv;

    // glds staging geometry: wave wv stages rows c = 8wv..8wv+8 (linear dest)
    const int c_row   = wv * 8 + (lane >> 3);
    const int src_col = 4 * (lane & 7);

    // converter geometry: thread -> (n, 8B chunk j), c0 = 4j
    const int cv_n  = tid & 31;
    const int cv_j  = 2 * (tid >> 6) + ((tid >> 5) & 1);
    const int cv_c0 = 4 * cv_j;
    const int cv_jp = cv_j ^ (cv_n & 6);

#define PSTAGE(buf, ks_)                                                         \
    glds16(X + (size_t)((ks_) * 32 + c_row) * N_ + n0 + src_col,                 \
           &Xf[buf][wv * 256])

#define PCONV(dst, src)                                                          \
    do {                                                                         \
        float x0 = Xf[src][(cv_c0 + 0) * 32 + cv_n];                             \
        float x1 = Xf[src][(cv_c0 + 1) * 32 + cv_n];                             \
        float x2 = Xf[src][(cv_c0 + 2) * 32 + cv_n];                             \
        float x3 = Xf[src][(cv_c0 + 3) * 32 + cv_n];                             \
        uint2 w_;                                                                \
        w_.x = (uint)f2bf(x0) | ((uint)f2bf(x1) << 16);                          \
        w_.y = (uint)f2bf(x2) | ((uint)f2bf(x3) << 16);                          \
        *(uint2*)&Xb[dst][cv_n * 32 + cv_jp * 4] = w_;                           \
    } while (0)

    PSTAGE(0, 0);
    __syncthreads();
    PSTAGE(1, 1);
    PCONV(0, 0);
    __syncthreads();

    const f32x4 zv = {0.f, 0.f, 0.f, 0.f};
    f32x4 acc[4][2] = {{zv, zv}, {zv, zv}, {zv, zv}, {zv, zv}};

    int pb = 0, pf = 1;
    for (int ks = 0; ks < 8; ++ks) {
        if (ks + 2 < 8) PSTAGE(pf ^ 1, ks + 2);
        if (ks + 1 < 8) PCONV(pb ^ 1, pf);

        // frags: lane (li,g,nf): row n=16nf+li, 16B chunk (2g)^(n&6) -> c=8g..8g+7
        bf16x8 xb[2];
#pragma unroll
        for (int nf = 0; nf < 2; ++nf)
            xb[nf] = *(const bf16x8*)&Xb[pb][(16 * nf + li) * 32 + 4 * ((2 * g) ^ (li & 6))];

        const size_t abase = ((size_t)(ks * 16 + wv * 4) * 64 + lane) * 8;
        __builtin_amdgcn_s_setprio(1);
#pragma unroll
        for (int ot = 0; ot < 4; ++ot) {
            const bf16x8 ah = *(const bf16x8*)(Wh + abase + (size_t)ot * 512);
            const bf16x8 al = *(const bf16x8*)(Wl + abase + (size_t)ot * 512);
#pragma unroll
            for (int nf = 0; nf < 2; ++nf) {
                f32x4 a = acc[ot][nf];
                a = __builtin_amdgcn_mfma_f32_16x16x32_bf16(al, xb[nf], a, 0, 0, 0);
                a = __builtin_amdgcn_mfma_f32_16x16x32_bf16(ah, xb[nf], a, 0, 0, 0);
                acc[ot][nf] = a;
            }
        }
        __builtin_amdgcn_s_setprio(0);
        __syncthreads();
        pb ^= 1;
        pf ^= 1;
    }

    // ---- epilogue: bias (+scale for Q), stage bf16 tile Ls[n][o]
    const float scale = (sel == 0) ? QSCALE : 1.0f;
#pragma unroll
    for (int ot = 0; ot < 4; ++ot)
#pragma unroll
        for (int nf = 0; nf < 2; ++nf)
#pragma unroll
            for (int r = 0; r < 4; ++r) {
                const int o = wv * 64 + ot * 16 + g * 4 + r;
                Ls[nf * 16 + li][o] = f2bf((acc[ot][nf][r] + bias[o]) * scale);
            }
    __syncthreads();

    const int h  = tid >> 6;
    const int bh = b * 4 + h;
    if (sel == 0) {
#pragma unroll
        for (int r_ = 0; r_ < 4; ++r_) {
            const int gi = (tid & 63) + 64 * r_;
            const int n_l = gi >> 3, dr = gi & 7;
            ushort u[8];
#pragma unroll
            for (int e = 0; e < 8; ++e) u[e] = Ls[n_l][(dr * 8 + e) * 4 + h];
            *(uint4*)(Qb + (((size_t)bh * N_) + n0 + n_l) * 64 + dr * 8) = pack8(u);
        }
    } else if (sel == 1) {
#pragma unroll
        for (int r_ = 0; r_ < 4; ++r_) {
            const int gi = (tid & 63) + 64 * r_;
            const int n_l = gi >> 3, dr = gi & 7;
            ushort u[8];
#pragma unroll
            for (int e = 0; e < 8; ++e) u[e] = Ls[n_l][(dr * 8 + e) * 4 + h];
            const int jg    = n0 + n_l;
            const int j     = jg & 63;
            const int ktile = jg >> 6;
            *(uint4*)(Kimg + (((size_t)bh * 32 + ktile) << 12) + j * 64 +
                      ((dr * 8) ^ ((j & 7) << 3))) = pack8(u);
        }
    } else {
#pragma unroll
        for (int r_ = 0; r_ < 4; ++r_) {
            const int gi = (tid & 63) + 64 * r_;
            const int d = gi >> 2, jr = gi & 3;
            ushort u[8];
#pragma unroll
            for (int e = 0; e < 8; ++e) u[e] = Ls[jr * 8 + e][d * 4 + h];
            const int jbase = (nt & 1) * 32 + jr * 8;
            const int ktile = nt >> 1;
            *(uint4*)(Vimg + (((size_t)bh * 32 + ktile) << 12) + d * 64 +
                      (jbase ^ ((d & 7) << 3))) = pack8(u);
        }
    }
#undef PSTAGE
#undef PCONV
}

// ---------------------------------------------------------------------------
// attn_v6: split-K flash attention, max-free softmax, 64-query tiles.
// K/V double-buffered via global_load_lds, ONE barrier per tile (loads stay
// in flight under compute). setprio around MFMA clusters. LDS 40KB ->
// exactly 4 blocks/CU. Writes unnormalized Opart[slot][q16][d64] + lpart.
// ---------------------------------------------------------------------------
__global__ __launch_bounds__(256) void attn_v6(const ushort* __restrict__ Qb,
                                               const ushort* __restrict__ Kimg,
                                               const ushort* __restrict__ Vimg,
                                               float* __restrict__ Opart,
                                               float* __restrict__ lpart) {
    __shared__ ushort SMEM[20480];   // K dbuf 16KB | V dbuf 16KB | P 8KB

    const int bid = blockIdx.x;
    const int xcd = bid & 7;
    const int r   = bid >> 3;                  // 0..127
    const int p   = xcd + 8 * (r >> 5);        // 0..31 : (bh,s) pair per XCD
    const int qt  = r & 31;
    const int bh  = p >> 1;
    const int s   = p & 1;

    const int tid  = threadIdx.x;
    const int wv   = tid >> 6;
    const int lane = tid & 63;
    const int li   = lane & 15;
    const int g    = lane >> 4;
    const int l7   = li & 7;
    const int i0w  = qt * 64 + wv * 16;

    bf16x8 qf[2];
#pragma unroll
    for (int ks = 0; ks < 2; ++ks)
        qf[ks] = *(const bf16x8*)(Qb + ((size_t)bh * N_ + i0w + li) * 64 + ks * 32 + g * 8);

    const ushort* Kg = Kimg + ((size_t)bh << 17);
    const ushort* Vg = Vimg + ((size_t)bh << 17);
    ushort* Pw = SMEM + 16384 + wv * 1024;     // 2KB/wave (16q x 64j bf16)

    const f32x4 z = {0.f, 0.f, 0.f, 0.f};
    f32x4 accO[4] = {z, z, z, z};
    f32x4 accL = z;
    const bf16x8 ones = {16256, 16256, 16256, 16256, 16256, 16256, 16256, 16256};

    const int kt0 = s * 16, kt1 = kt0 + 16;

#define STAGE(buf, kt_)                                                          \
    do {                                                                         \
        const ushort* ksrc = Kg + ((size_t)(kt_) << 12) + wv * 1024 + lane * 8;  \
        const ushort* vsrc = Vg + ((size_t)(kt_) << 12) + wv * 1024 + lane * 8;  \
        glds16(ksrc,       SMEM + (buf) * 4096 + wv * 1024);                     \
        glds16(ksrc + 512, SMEM + (buf) * 4096 + wv * 1024 + 512);               \
        glds16(vsrc,       SMEM + 8192 + (buf) * 4096 + wv * 1024);              \
        glds16(vsrc + 512, SMEM + 8192 + (buf) * 4096 + wv * 1024 + 512);        \
    } while (0)

    STAGE(0, kt0);
    __syncthreads();

    int cur = 0;
    for (int kt = kt0; kt < kt1; ++kt) {
        if (kt + 1 < kt1) STAGE(cur ^ 1, kt + 1);

        const ushort* Kc = SMEM + cur * 4096;
        const ushort* Vc = SMEM + 8192 + cur * 4096;

        // ---- QK^T: lane holds S^T[j=16jt+4g+r][q=li]
        f32x4 sc[4];
        __builtin_amdgcn_s_setprio(1);
#pragma unroll
        for (int jt = 0; jt < 4; ++jt) {
            const ushort* row = Kc + (16 * jt + li) * 64;
            const bf16x8 kf0 = *(const bf16x8*)(row + 8 * (g ^ l7));
            const bf16x8 kf1 = *(const bf16x8*)(row + 8 * ((4 + g) ^ l7));
            f32x4 a = z;
            a = __builtin_amdgcn_mfma_f32_16x16x32_bf16(kf0, qf[0], a, 0, 0, 0);
            a = __builtin_amdgcn_mfma_f32_16x16x32_bf16(kf1, qf[1], a, 0, 0, 0);
            sc[jt] = a;
        }
        __builtin_amdgcn_s_setprio(0);

        // ---- max-free softmax: p = exp2(s), write P^T to wave-private LDS
#pragma unroll
        for (int jt = 0; jt < 4; ++jt) {
            const float p0 = fexp2(sc[jt][0]);
            const float p1 = fexp2(sc[jt][1]);
            const float p2 = fexp2(sc[jt][2]);
            const float p3 = fexp2(sc[jt][3]);
            const uint a01 = (__float_as_uint(p1) & 0xffff0000u) | (__float_as_uint(p0) >> 16);
            const uint a23 = (__float_as_uint(p3) & 0xffff0000u) | (__float_as_uint(p2) >> 16);
            const uint byteoff = (uint)(li * 128) + (((uint)(jt * 32 + g * 8)) ^ ((uint)l7 << 4));
            *(uint2*)((char*)Pw + byteoff) = make_uint2(a01, a23);
        }

        const bf16x8 pf0 = *(const bf16x8*)((char*)Pw + li * 128 + 16 * (g ^ l7));
        const bf16x8 pf1 = *(const bf16x8*)((char*)Pw + li * 128 + 16 * ((4 + g) ^ l7));

        __builtin_amdgcn_s_setprio(1);
        accL = __builtin_amdgcn_mfma_f32_16x16x32_bf16(ones, pf0, accL, 0, 0, 0);
        accL = __builtin_amdgcn_mfma_f32_16x16x32_bf16(ones, pf1, accL, 0, 0, 0);

        // ---- PV
#pragma unroll
        for (int dt = 0; dt < 4; ++dt) {
            const ushort* row = Vc + (16 * dt + li) * 64;
            const bf16x8 vf0 = *(const bf16x8*)(row + 8 * (g ^ l7));
            const bf16x8 vf1 = *(const bf16x8*)(row + 8 * ((4 + g) ^ l7));
            f32x4 a = accO[dt];
            a = __builtin_amdgcn_mfma_f32_16x16x32_bf16(vf0, pf0, a, 0, 0, 0);
            a = __builtin_amdgcn_mfma_f32_16x16x32_bf16(vf1, pf1, a, 0, 0, 0);
            accO[dt] = a;
        }
        __builtin_amdgcn_s_setprio(0);

        __syncthreads();   // drains glds for buf^1 + all waves done reading buf
        cur ^= 1;
    }
#undef STAGE

    // ---- epilogue: unnormalized O^T -> Opart[slot][q][d] (d-contiguous)
    const int slot = ((s * 16 + bh) * 32 + qt) * 4 + wv;
    float* Op = Opart + (size_t)slot * 1024;
#pragma unroll
    for (int dt = 0; dt < 4; ++dt)
        *(f32x4*)&Op[li * 64 + dt * 16 + g * 4] = accO[dt];
    if (g == 0) lpart[slot * 16 + li] = accL[0];
}

// ---------------------------------------------------------------------------
// conv_out: fused split-combine + output projection (bf16 MFMA, 3-product).
// ---------------------------------------------------------------------------
__global__ __launch_bounds__(256) void conv_out(const float* __restrict__ Opart,
                                                const float* __restrict__ lpart,
                                                const ushort* __restrict__ Whimg,
                                                const ushort* __restrict__ Wlimg,
                                                const float* __restrict__ bm,
                                                float* __restrict__ out) {
    __shared__ ushort Bh[512 * 8];
    __shared__ ushort Bl[512 * 8];
    __shared__ float Linv[4][16];

    const int bx  = blockIdx.x;        // 0..127
    const int b   = blockIdx.y;        // 0..3
    const int n0  = bx * 16;
    const int qt  = bx >> 2;           // 64q-tile
    const int wq  = bx & 3;            // wave slot within tile
    const int tid = threadIdx.x;

    if (tid < 64) {
        const int h = tid >> 4, q = tid & 15;
        const int sl0 = (((0 * 16 + b * 4 + h) * 32 + qt) * 4 + wq);
        const int sl1 = (((1 * 16 + b * 4 + h) * 32 + qt) * 4 + wq);
        Linv[h][q] = 1.0f / (lpart[sl0 * 16 + q] + lpart[sl1 * 16 + q]);
    }
    __syncthreads();

#pragma unroll
    for (int it = 0; it < 4; ++it) {
        const int id = tid + 256 * it;        // 0..1023 = (h,q,d4)
        const int h  = id >> 8;
        const int q  = (id >> 4) & 15;
        const int d4 = id & 15;
        const size_t sl0 = (size_t)(((0 * 16 + b * 4 + h) * 32 + qt) * 4 + wq);
        const size_t sl1 = (size_t)(((1 * 16 + b * 4 + h) * 32 + qt) * 4 + wq);
        const f32x4 v0 = *(const f32x4*)&Opart[sl0 * 1024 + q * 64 + d4 * 4];
        const f32x4 v1 = *(const f32x4*)&Opart[sl1 * 1024 + q * 64 + d4 * 4];
        const float li_ = Linv[h][q];
#pragma unroll
        for (int e = 0; e < 4; ++e) {
            const int d = d4 * 4 + e;
            const float vv = (v0[e] + v1[e]) * li_;
            const ushort hi = f2bf(vv);
            const ushort lo = f2bf(vv - bf2f(hi));
            const int cg = d >> 1;
            const int eb = (d & 1) * 4 + h;
            const int Gp = (q * 32 + cg) ^ (q & 7);
            Bh[Gp * 8 + eb] = hi;
            Bl[Gp * 8 + eb] = lo;
        }
    }
    __syncthreads();

    const int wv = tid >> 6, lane = tid & 63, li = lane & 15, g = lane >> 4;
    const ushort* Wh = Whimg + 3 * 65536;
    const ushort* Wl = Wlimg + 3 * 65536;
    const f32x4 zv = {0.f, 0.f, 0.f, 0.f};
    f32x4 acc[4] = {zv, zv, zv, zv};

    for (int ks = 0; ks < 8; ++ks) {
        const int Gp = (li * 32 + ks * 4 + g) ^ (li & 7);
        const bf16x8 bh_ = *(const bf16x8*)(Bh + Gp * 8);
        const bf16x8 bl_ = *(const bf16x8*)(Bl + Gp * 8);
        const size_t abase = ((size_t)(ks * 16 + wv * 4) * 64 + lane) * 8;
#pragma unroll
        for (int ot = 0; ot < 4; ++ot) {
            const bf16x8 ah = *(const bf16x8*)(Wh + abase + (size_t)ot * 512);
            const bf16x8 al = *(const bf16x8*)(Wl + abase + (size_t)ot * 512);
            f32x4 a = acc[ot];
            a = __builtin_amdgcn_mfma_f32_16x16x32_bf16(ah, bl_, a, 0, 0, 0);
            a = __builtin_amdgcn_mfma_f32_16x16x32_bf16(al, bh_, a, 0, 0, 0);
            a = __builtin_amdgcn_mfma_f32_16x16x32_bf16(ah, bh_, a, 0, 0, 0);
            acc[ot] = a;
        }
    }

#pragma unroll
    for (int ot = 0; ot < 4; ++ot)
#pragma unroll
        for (int r = 0; r < 4; ++r) {
            const int o = wv * 64 + ot * 16 + g * 4 + r;
            out[((size_t)(b * 256 + o)) * N_ + n0 + li] = acc[ot][r] + bm[o];
        }
}

// ---------------------------------------------------------------------------
extern "C" void kernel_launch(void* const* d_in, const int* in_sizes, int n_in,
                              void* d_out, int out_size, void* d_ws, size_t ws_size,
                              hipStream_t stream) {
    const float* query = (const float*)d_in[0];
    const float* key   = (const float*)d_in[1];
    const float* value = (const float*)d_in[2];
    const float* wq = (const float*)d_in[3];
    const float* bq = (const float*)d_in[4];
    const float* wk = (const float*)d_in[5];
    const float* bk = (const float*)d_in[6];
    const float* wv = (const float*)d_in[7];
    const float* bv = (const float*)d_in[8];
    const float* wm = (const float*)d_in[9];
    const float* bm = (const float*)d_in[10];

    float* out = (float*)d_out;
    char*  ws  = (char*)d_ws;

    const size_t TEN = (size_t)B_ * C_ * N_;            // 2,097,152

    float*  Opart = (float*)ws;
    float*  lpart = (float*)(ws + (size_t)4096 * 1024 * 4);
    ushort* Qb    = (ushort*)(ws + (size_t)4096 * 1024 * 4 + 262144);
    ushort* Kimg  = Qb + TEN;
    ushort* Vimg  = Kimg + TEN;
    ushort* Whimg = Vimg + TEN;
    ushort* Wlimg = Whimg + 4 * 65536;

    pack_w<<<dim3(4, 8), dim3(256), 0, stream>>>(wq, wk, wv, wm, Whimg, Wlimg);
    proj_fused<<<dim3(64, 1, 12), dim3(256), 0, stream>>>(query, key, value,
                                                          Whimg, Wlimg, bq, bk, bv,
                                                          Qb, Kimg, Vimg);
    attn_v6<<<dim3(1024), dim3(256), 0, stream>>>(Qb, Kimg, Vimg, Opart, lpart);
    conv_out<<<dim3(128, 4), dim3(256), 0, stream>>>(Opart, lpart, Whimg, Wlimg, bm, out);
}